// Round 5
// baseline (6944.041 us; speedup 1.0000x reference)
//
#include <hip/hip_runtime.h>
#include <hip/hip_bf16.h>

// BERT stack: L=12(+1 dup of layer0), H=12, E=768, D=64, B=4, S=512 -> BS=2048 tokens.
// Faithful bugs preserved:
//  - attention flattens batch: 2048 tokens attend to each other globally, q==k==v
//  - zc = z.reshape(768,2048) is a FLAT VIEW of z[H][N][D]  (no transpose)
//  - mh = (wo@zc).reshape(B,S,E) is a FLAT VIEW of mh_mat[768][2048]
//  - pe: p = 10000 for e<384 else 10001; even e -> sin, odd -> cos; s = t % 512
// R1: reg-prefetch pipeline. R2: native f2bf, exp2 softmax, wave-per-token LN.
// R3: LDS-only barriers (BAR), true double-buffer, attn Q-tile 128 ksplit=4.
// R1-R3 all NEUTRAL (1170->1161): inner loops exonerated; 81 dispatches x
// ~14us avg => dispatch overhead dominates.
// R4 (resubmitted R5 after infra timeout): ONE persistent kernel for all 13
// layers (grid=384, launch_bounds(256,2) -> >=2 blocks/CU co-resident,
// deadlock-safe; 48KB LDS -> 3/CU LDS-wise). Device-scope atomic grid
// barrier (release/acquire + threadfence both sides for cross-XCD L2,
// monotone counter zeroed by pe_add each replay): 81 dispatches -> 4.

#define BS_TOK 2048
#define EMB 768
#define NH 12
#define HD 64
#define WQN (12 * NH * EMB * HD)  // elems per weight stack (7077888)
#define NBLK 384

typedef __attribute__((ext_vector_type(8))) short bf16x8;
typedef __attribute__((ext_vector_type(4))) short bf16x4;
typedef __attribute__((ext_vector_type(4))) float f32x4;

__device__ __forceinline__ short f2bf(float f) {
  union { __hip_bfloat16 h; short s; } u;
  u.h = __float2bfloat16(f);
  return u.s;
}

#define MFMA16(a, b, c) __builtin_amdgcn_mfma_f32_16x16x32_bf16(a, b, c, 0, 0, 0)
// XOR-swizzled LDS address for [r][k] tiles, 64-elem rows (zero-conflict)
#define SW64(r, k) ((r) * 64 + ((((k) >> 3) ^ ((r) & 7)) << 3) + ((k) & 7))
// Barrier that drains LDS ops only — in-flight global loads cross it.
#define BAR() asm volatile("s_waitcnt lgkmcnt(0)\n\ts_barrier" ::: "memory")

// Device-scope grid barrier: monotone counter, agent-scope release/acquire.
__device__ __forceinline__ void gridbar(unsigned* cnt, unsigned& ph) {
  __syncthreads();  // all block stores issued & complete (vmcnt drain)
  if (threadIdx.x == 0) {
    __threadfence();  // L2 writeback (cross-XCD visibility of our stores)
    __hip_atomic_fetch_add(cnt, 1u, __ATOMIC_RELEASE, __HIP_MEMORY_SCOPE_AGENT);
    unsigned tgt = (++ph) * (unsigned)NBLK;
    while (__hip_atomic_load(cnt, __ATOMIC_ACQUIRE, __HIP_MEMORY_SCOPE_AGENT) < tgt)
      __builtin_amdgcn_s_sleep(16);
    __threadfence();  // L2 invalidate (see other XCDs' stores)
  }
  __syncthreads();
}

// ---------------------------------------------------------------- weight prep
__global__ __launch_bounds__(256) void cvt_weights_kernel(const float* __restrict__ wo,
                                                          const float* __restrict__ fw,
                                                          short* __restrict__ wob,
                                                          short* __restrict__ fwb) {
  const float* src = blockIdx.y ? fw : wo;
  short* dst = blockIdx.y ? fwb : wob;
  int i = (blockIdx.x * 256 + threadIdx.x) * 8;
  float4 a = *(const float4*)(src + i);
  float4 b = *(const float4*)(src + i + 4);
  bf16x8 t;
  t[0] = f2bf(a.x); t[1] = f2bf(a.y); t[2] = f2bf(a.z); t[3] = f2bf(a.w);
  t[4] = f2bf(b.x); t[5] = f2bf(b.y); t[6] = f2bf(b.z); t[7] = f2bf(b.w);
  *(bf16x8*)(dst + i) = t;
}

// wqT[l][h][d][e] <- wq[l][h][e][d], bf16
__global__ __launch_bounds__(256) void wq_trans_kernel(const float* __restrict__ wq,
                                                       short* __restrict__ wqT) {
  __shared__ short T[64 * 64];
  const int et = blockIdx.x;  // e-tile (12)
  const int lh = blockIdx.y;  // l*NH+h (144)
  const int tid = threadIdx.x;
  const float* src = wq + ((size_t)lh * EMB + et * 64) * HD;
  {
    int r = tid >> 2, c16 = (tid & 3) << 4;
    const float* p = src + r * HD + c16;
    float4 x0 = *(const float4*)(p + 0);
    float4 x1 = *(const float4*)(p + 4);
    float4 x2 = *(const float4*)(p + 8);
    float4 x3 = *(const float4*)(p + 12);
    bf16x8 a, b;
    a[0] = f2bf(x0.x); a[1] = f2bf(x0.y); a[2] = f2bf(x0.z); a[3] = f2bf(x0.w);
    a[4] = f2bf(x1.x); a[5] = f2bf(x1.y); a[6] = f2bf(x1.z); a[7] = f2bf(x1.w);
    b[0] = f2bf(x2.x); b[1] = f2bf(x2.y); b[2] = f2bf(x2.z); b[3] = f2bf(x2.w);
    b[4] = f2bf(x3.x); b[5] = f2bf(x3.y); b[6] = f2bf(x3.w ? x3.w : x3.w); b[6] = f2bf(x3.z); b[7] = f2bf(x3.w);
    int g = c16 >> 3;
    *(bf16x8*)&T[r * 64 + ((g ^ (r & 7)) << 3)] = a;
    *(bf16x8*)&T[r * 64 + (((g + 1) ^ (r & 7)) << 3)] = b;
  }
  __syncthreads();
  {
    int d = tid >> 2, e16 = (tid & 3) << 4;
    bf16x8 t0, t1;
#pragma unroll
    for (int j = 0; j < 8; ++j) t0[j] = T[SW64(e16 + j, d)];
#pragma unroll
    for (int j = 0; j < 8; ++j) t1[j] = T[SW64(e16 + 8 + j, d)];
    short* q = wqT + ((size_t)lh * HD + d) * EMB + et * 64 + e16;
    *(bf16x8*)(q) = t0;
    *(bf16x8*)(q + 8) = t1;
  }
}

// ------------------------------------------- pe + tokens (+ barrier counter init)
__global__ __launch_bounds__(256) void pe_add_kernel(const float* __restrict__ tok,
                                                     float* __restrict__ X,
                                                     short* __restrict__ Xb,
                                                     unsigned* __restrict__ barcnt) {
  int idx = blockIdx.x * 256 + threadIdx.x;   // < 2048*768
  if (idx == 0) *barcnt = 0;                  // re-zero each graph replay
  int e = idx % EMB;
  int t = idx / EMB;
  int s = t & 511;                            // t = b*512 + s
  float p = (e < 384) ? 10000.0f : 10001.0f;  // 10000 XOR ((2e)//768)
  float ang = (float)s / p;
  float pe = (e & 1) ? cosf(ang) : sinf(ang);
  float v = tok[idx] + pe;
  X[idx] = v;
  Xb[idx] = f2bf(v);
}

// ---------------- staging helpers (split load/write for reg-prefetch pipeline)
__device__ __forceinline__ void load64(const short* __restrict__ src, int ld,
                                       int row0, int k0, bf16x8* r, int tid) {
  int rr = tid >> 2, kb = (tid & 3) << 4;
  const short* p = src + (size_t)(row0 + rr) * ld + k0 + kb;
  r[0] = *(const bf16x8*)(p);
  r[1] = *(const bf16x8*)(p + 8);
}
__device__ __forceinline__ void write64(short* dst, const bf16x8* r, int tid) {
  int rr = tid >> 2, g = (tid & 3) << 1;
  *(bf16x8*)&dst[rr * 64 + (((g + 0) ^ (rr & 7)) << 3)] = r[0];
  *(bf16x8*)&dst[rr * 64 + (((g + 1) ^ (rr & 7)) << 3)] = r[1];
}

__device__ __forceinline__ void load128(const short* __restrict__ src, int ld,
                                        int row0, int k0, bf16x8* r, int tid) {
  int rr = tid >> 1, kb = (tid & 1) << 5;
  const short* p = src + (size_t)(row0 + rr) * ld + k0 + kb;
  r[0] = *(const bf16x8*)(p);
  r[1] = *(const bf16x8*)(p + 8);
  r[2] = *(const bf16x8*)(p + 16);
  r[3] = *(const bf16x8*)(p + 24);
}
__device__ __forceinline__ void write128(short* dst, const bf16x8* r, int tid) {
  int rr = tid >> 1, g = (tid & 1) << 2;
#pragma unroll
  for (int i = 0; i < 4; ++i)
    *(bf16x8*)&dst[rr * 64 + (((g + i) ^ (rr & 7)) << 3)] = r[i];
}

// fused 4-way combine+transpose staging for gemm_out
__device__ __forceinline__ void load_comb(const float* __restrict__ Op,
                                          const float* __restrict__ Lp,
                                          int k0, int col0, float4 a[4][4],
                                          float& rl, int tid) {
  const int NB = BS_TOK * EMB;
  const int NHT = NH * BS_TOK;
  int kk = tid >> 2, nb = (tid & 3) << 4;
  size_t base = (size_t)(k0 + kk) * BS_TOK + col0 + nb;
  int hq = (int)(base >> 6);
  rl = 1.0f / ((Lp[hq] + Lp[hq + NHT]) + (Lp[hq + 2 * NHT] + Lp[hq + 3 * NHT]));
#pragma unroll
  for (int z = 0; z < 4; ++z)
#pragma unroll
    for (int q4 = 0; q4 < 4; ++q4)
      a[z][q4] = *(const float4*)(Op + base + (size_t)z * NB + q4 * 4);
}
__device__ __forceinline__ void write_comb(short* dst, const float4 a[4][4],
                                           float rl, int tid) {
  int kk = tid >> 2, nb = (tid & 3) << 4;
#pragma unroll
  for (int q4 = 0; q4 < 4; ++q4) {
    dst[SW64(nb + q4 * 4 + 0, kk)] =
        f2bf(((a[0][q4].x + a[1][q4].x) + (a[2][q4].x + a[3][q4].x)) * rl);
    dst[SW64(nb + q4 * 4 + 1, kk)] =
        f2bf(((a[0][q4].y + a[1][q4].y) + (a[2][q4].y + a[3][q4].y)) * rl);
    dst[SW64(nb + q4 * 4 + 2, kk)] =
        f2bf(((a[0][q4].z + a[1][q4].z) + (a[2][q4].z + a[3][q4].z)) * rl);
    dst[SW64(nb + q4 * 4 + 3, kk)] =
        f2bf(((a[0][q4].w + a[1][q4].w) + (a[2][q4].w + a[3][q4].w)) * rl);
  }
}

#define GEMM_TILE_COMPUTE(As, Bs, acc)                                              \
  {                                                                                 \
    _Pragma("unroll") for (int s = 0; s < 2; ++s) {                                 \
      int ra = (w << 4) + l15;                                                      \
      bf16x8 af = *(const bf16x8*)&As[ra * 64 + ((((s << 2) + quad) ^ (ra & 7)) << 3)]; \
      _Pragma("unroll") for (int nt = 0; nt < 4; ++nt) {                            \
        int rb = (nt << 4) + l15;                                                   \
        bf16x8 bf = *(const bf16x8*)&Bs[rb * 64 + ((((s << 2) + quad) ^ (rb & 7)) << 3)]; \
        acc[nt] = MFMA16(af, bf, acc[nt]);                                          \
      }                                                                             \
    }                                                                               \
  }

#define GEMM_TILE_COMPUTE2(As, Bs, acc)                                             \
  {                                                                                 \
    _Pragma("unroll") for (int s = 0; s < 2; ++s) {                                 \
      bf16x8 af[2];                                                                 \
      _Pragma("unroll") for (int u = 0; u < 2; ++u) {                               \
        int ra = (w << 5) + (u << 4) + l15;                                         \
        af[u] = *(const bf16x8*)&As[ra * 64 + ((((s << 2) + quad) ^ (ra & 7)) << 3)]; \
      }                                                                             \
      _Pragma("unroll") for (int nt = 0; nt < 4; ++nt) {                            \
        int rb = (nt << 4) + l15;                                                   \
        bf16x8 bf = *(const bf16x8*)&Bs[rb * 64 + ((((s << 2) + quad) ^ (rb & 7)) << 3)]; \
        acc[0][nt] = MFMA16(af[0], bf, acc[0][nt]);                                 \
        acc[1][nt] = MFMA16(af[1], bf, acc[1][nt]);                                 \
      }                                                                             \
    }                                                                               \
  }

// ------------------------------------------------- phase: Q = Xb * WqT
__device__ void phase_gemm_q(const short* __restrict__ Xb,
                             const short* __restrict__ WqT,
                             short* __restrict__ Qo, short* __restrict__ Qt,
                             int u, int tid, short* sm) {
  short* As[2] = {sm, sm + 4096};
  short* Bs[2] = {sm + 8192, sm + 12288};
  const int m0 = (u & 31) * 64;  // token tile
  const int h = u >> 5;          // head
  const int w = tid >> 6, lane = tid & 63, l15 = lane & 15, quad = lane >> 4;
  const short* wqh = WqT + (size_t)h * (HD * EMB);  // [d][e]
  f32x4 acc[4] = {};
  bf16x8 ar[2], br[2];
  load64(Xb, EMB, m0, 0, ar, tid);
  load64(wqh, EMB, 0, 0, br, tid);
  write64(As[0], ar, tid);
  write64(Bs[0], br, tid);
  load64(Xb, EMB, m0, 64, ar, tid);
  load64(wqh, EMB, 0, 64, br, tid);
  BAR();
  for (int k0 = 0; k0 < EMB; k0 += 64) {
    const int cur = (k0 >> 6) & 1;
    const short* Ac = As[cur];
    const short* Bc = Bs[cur];
    GEMM_TILE_COMPUTE(Ac, Bc, acc);
    if (k0 + 64 < EMB) {
      write64(As[cur ^ 1], ar, tid);
      write64(Bs[cur ^ 1], br, tid);
      if (k0 + 128 < EMB) {
        load64(Xb, EMB, m0, k0 + 128, ar, tid);
        load64(wqh, EMB, 0, k0 + 128, br, tid);
      }
    }
    BAR();
  }
  short* T = As[0];
#pragma unroll
  for (int nt = 0; nt < 4; ++nt)
#pragma unroll
    for (int r = 0; r < 4; ++r)
      T[SW64((w << 4) + (quad << 2) + r, (nt << 4) + l15)] = f2bf(acc[nt][r]);
  __syncthreads();
  {  // Qo[h][tok][d]
    int r2 = tid >> 2, kb = (tid & 3) << 4;
    int g = kb >> 3;
    bf16x8 q0v = *(const bf16x8*)&T[r2 * 64 + ((g ^ (r2 & 7)) << 3)];
    bf16x8 q1v = *(const bf16x8*)&T[r2 * 64 + (((g + 1) ^ (r2 & 7)) << 3)];
    short* qo = Qo + (size_t)h * (BS_TOK * HD) + (size_t)(m0 + r2) * HD + kb;
    *(bf16x8*)(qo) = q0v;
    *(bf16x8*)(qo + 8) = q1v;
  }
  {  // Qt[h][d][tok]
    int d = tid >> 2, tok0 = (tid & 3) << 4;
    bf16x8 t0, t1;
#pragma unroll
    for (int j = 0; j < 8; ++j) t0[j] = T[SW64(tok0 + j, d)];
#pragma unroll
    for (int j = 0; j < 8; ++j) t1[j] = T[SW64(tok0 + 8 + j, d)];
    short* qt = Qt + (size_t)h * (HD * BS_TOK) + (size_t)d * BS_TOK + m0 + tok0;
    *(bf16x8*)(qt) = t0;
    *(bf16x8*)(qt + 8) = t1;
  }
}

// ------------------------------------------------- phase: flash attention
__device__ void phase_attn(const short* __restrict__ Q,
                           const short* __restrict__ Qt,
                           float* __restrict__ Opart, float* __restrict__ Lpart,
                           int u, int tid, short* sm) {
  short* Ks[2] = {sm, sm + 4096};
  short* Vt[2] = {sm + 8192, sm + 12288};
  short* Pw = sm + 16384;
  const int h = (u >> 4) % NH;
  const int q0 = (u & 15) * 128;
  const int kt0 = (u / 192) * 8;  // 8 K-tiles per split
  const int lane = tid & 63;
  const int wv = tid >> 6;
  const int l15 = lane & 15;
  const int quad = lane >> 4;
  const short* Qh = Q + (size_t)h * (BS_TOK * HD);
  const short* Qth = Qt + (size_t)h * (HD * BS_TOK);
  short* myP = Pw + wv * 2048;

  bf16x8 qf[2][2];
#pragma unroll
  for (int sub = 0; sub < 2; ++sub) {
    const short* qp = Qh + (size_t)(q0 + wv * 32 + sub * 16 + l15) * HD + quad * 8;
    qf[sub][0] = *(const bf16x8*)(qp);
    qf[sub][1] = *(const bf16x8*)(qp + 32);
  }

  f32x4 o[2][4] = {};
  float lpl[2] = {0.f, 0.f};

  bf16x8 kreg[2], vreg[2];
#pragma unroll
  for (int i = 0; i < 2; ++i) {
    int c = i * 256 + tid;
    kreg[i] = *(const bf16x8*)(Qh + (size_t)kt0 * 4096 + c * 8);
    vreg[i] = *(const bf16x8*)(Qth + (size_t)(c >> 3) * BS_TOK + kt0 * 64 + (c & 7) * 8);
  }
#pragma unroll
  for (int i = 0; i < 2; ++i) {
    int c = i * 256 + tid, row = c >> 3, g = c & 7;
    *(bf16x8*)&Ks[0][row * 64 + ((g ^ (row & 7)) << 3)] = kreg[i];
    *(bf16x8*)&Vt[0][row * 64 + ((g ^ (row & 7)) << 3)] = vreg[i];
  }
#pragma unroll
  for (int i = 0; i < 2; ++i) {
    int c = i * 256 + tid;
    kreg[i] = *(const bf16x8*)(Qh + (size_t)(kt0 + 1) * 4096 + c * 8);
    vreg[i] = *(const bf16x8*)(Qth + (size_t)(c >> 3) * BS_TOK + (kt0 + 1) * 64 + (c & 7) * 8);
  }
  BAR();

  for (int kt = 0; kt < 8; ++kt) {
    const short* K_ = Ks[kt & 1];
    const short* V_ = Vt[kt & 1];

    f32x4 s[2][4];
    __builtin_amdgcn_s_setprio(1);
#pragma unroll
    for (int ct = 0; ct < 4; ++ct) {
      int row = ct * 16 + l15;
      bf16x8 kf0 = *(const bf16x8*)(&K_[row * 64 + ((quad ^ (row & 7)) << 3)]);
      bf16x8 kf1 = *(const bf16x8*)(&K_[row * 64 + (((4 + quad) ^ (row & 7)) << 3)]);
#pragma unroll
      for (int sub = 0; sub < 2; ++sub) {
        f32x4 a = (f32x4){0.f, 0.f, 0.f, 0.f};
        a = MFMA16(kf0, qf[sub][0], a);
        a = MFMA16(kf1, qf[sub][1], a);
        s[sub][ct] = a;
      }
    }
    __builtin_amdgcn_s_setprio(0);

#pragma unroll
    for (int sub = 0; sub < 2; ++sub) {
      int prow = sub * 16 + l15;
#pragma unroll
      for (int ct = 0; ct < 4; ++ct) {
        bf16x4 pv4;
#pragma unroll
        for (int r = 0; r < 4; ++r) {
          float p = exp2f(s[sub][ct][r] * 0.18033688011112042f);
          lpl[sub] += p;
          pv4[r] = f2bf(p);
        }
        int g = 2 * ct + (quad >> 1);
        *(bf16x4*)&myP[prow * 64 + ((g ^ (prow & 7)) << 3) + ((quad & 1) << 2)] = pv4;
      }
    }

    __builtin_amdgcn_s_setprio(1);
#pragma unroll
    for (int ks = 0; ks < 2; ++ks) {
      int c = ks * 4 + quad;
      bf16x8 pf0 = *(const bf16x8*)(&myP[l15 * 64 + ((c ^ (l15 & 7)) << 3)]);
      bf16x8 pf1 = *(const bf16x8*)(&myP[(16 + l15) * 64 + ((c ^ (l15 & 7)) << 3)]);
#pragma unroll
      for (int dt = 0; dt < 4; ++dt) {
        int row = dt * 16 + l15;
        bf16x8 vf = *(const bf16x8*)(&V_[row * 64 + ((c ^ (row & 7)) << 3)]);
        o[0][dt] = MFMA16(pf0, vf, o[0][dt]);
        o[1][dt] = MFMA16(pf1, vf, o[1][dt]);
      }
    }
    __builtin_amdgcn_s_setprio(0);

    if (kt + 1 < 8) {
      short* Kn = Ks[(kt & 1) ^ 1];
      short* Vn = Vt[(kt & 1) ^ 1];
#pragma unroll
      for (int i = 0; i < 2; ++i) {
        int c = i * 256 + tid, row = c >> 3, g = c & 7;
        *(bf16x8*)&Kn[row * 64 + ((g ^ (row & 7)) << 3)] = kreg[i];
        *(bf16x8*)&Vn[row * 64 + ((g ^ (row & 7)) << 3)] = vreg[i];
      }
      if (kt + 2 < 8) {
        int gt = kt0 + kt + 2;
#pragma unroll
        for (int i = 0; i < 2; ++i) {
          int c = i * 256 + tid;
          kreg[i] = *(const bf16x8*)(Qh + (size_t)gt * 4096 + c * 8);
          vreg[i] = *(const bf16x8*)(Qth + (size_t)(c >> 3) * BS_TOK + gt * 64 + (c & 7) * 8);
        }
      }
    }
    BAR();
  }

#pragma unroll
  for (int sub = 0; sub < 2; ++sub) {
    lpl[sub] += __shfl_xor(lpl[sub], 16, 64);
    lpl[sub] += __shfl_xor(lpl[sub], 32, 64);
  }

  const int NB = BS_TOK * EMB;
  const int z = u / 192;
  float* Oh = Opart + (size_t)z * NB + (size_t)h * (BS_TOK * HD);
  float* Lh = Lpart + ((size_t)z * NH + h) * BS_TOK;
  if (quad == 0) {
    Lh[q0 + wv * 32 + l15] = lpl[0];
    Lh[q0 + wv * 32 + 16 + l15] = lpl[1];
  }
#pragma unroll
  for (int sub = 0; sub < 2; ++sub)
#pragma unroll
    for (int r = 0; r < 4; ++r) {
      int qrow = q0 + wv * 32 + sub * 16 + quad * 4 + r;
#pragma unroll
      for (int dt = 0; dt < 4; ++dt)
        Oh[(size_t)qrow * HD + dt * 16 + l15] = o[sub][dt][r];
    }
}

// ------------------------------------------------- phase: MH = Wo * combine/l
__device__ void phase_gemm_out(const short* __restrict__ Wob,
                               const float* __restrict__ Op,
                               const float* __restrict__ Lp,
                               float* __restrict__ Pp,
                               int u, int tid, short* sm) {
  short* As[2] = {sm, sm + 8192};
  short* Bs[2] = {sm + 16384, sm + 20480};
  const int n0 = (u % 32) * 64;
  const int m0 = ((u / 32) % 6) * 128;
  const int kz = (u / 192) * 384;
  const int w = tid >> 6, lane = tid & 63, l15 = lane & 15, quad = lane >> 4;
  f32x4 acc[2][4] = {};
  bf16x8 ar[4];
  float4 ca[4][4];
  float rl;
  load128(Wob, EMB, m0, kz, ar, tid);
  load_comb(Op, Lp, kz, n0, ca, rl, tid);
  write128(As[0], ar, tid);
  write_comb(Bs[0], ca, rl, tid);
  load128(Wob, EMB, m0, kz + 64, ar, tid);
  load_comb(Op, Lp, kz + 64, n0, ca, rl, tid);
  BAR();
  for (int k0 = 0; k0 < 384; k0 += 64) {
    const int cur = (k0 >> 6) & 1;
    const short* Ac = As[cur];
    const short* Bc = Bs[cur];
    GEMM_TILE_COMPUTE2(Ac, Bc, acc);
    if (k0 + 64 < 384) {
      write128(As[cur ^ 1], ar, tid);
      write_comb(Bs[cur ^ 1], ca, rl, tid);
      if (k0 + 128 < 384) {
        load128(Wob, EMB, m0, kz + k0 + 128, ar, tid);
        load_comb(Op, Lp, kz + k0 + 128, n0, ca, rl, tid);
      }
    }
    BAR();
  }
  float* P = Pp + (size_t)(u / 192) * (BS_TOK * EMB);
#pragma unroll
  for (int uu = 0; uu < 2; ++uu)
#pragma unroll
    for (int nt = 0; nt < 4; ++nt)
#pragma unroll
      for (int r = 0; r < 4; ++r)
        P[(size_t)(m0 + (w << 5) + (uu << 4) + (quad << 2) + r) * BS_TOK + n0 +
          (nt << 4) + l15] = acc[uu][nt][r];
}

// ------------------------------------------------- phase: FFN
__device__ void phase_ffn(const short* __restrict__ L1b,
                          const short* __restrict__ Fwb,
                          const float* __restrict__ Fb,
                          float* __restrict__ Pp,
                          int u, int tid, short* sm) {
  short* As[2] = {sm, sm + 8192};
  short* Bs[2] = {sm + 16384, sm + 20480};
  const int m0 = (u % 16) * 128;
  const int n0 = ((u / 16) % 12) * 64;
  const int kz = (u / 192) * 384;
  const int w = tid >> 6, lane = tid & 63, l15 = lane & 15, quad = lane >> 4;
  f32x4 acc[2][4] = {};
  bf16x8 ar[4], br[2];
  load128(L1b, EMB, m0, kz, ar, tid);
  load64(Fwb, EMB, n0, kz, br, tid);
  write128(As[0], ar, tid);
  write64(Bs[0], br, tid);
  load128(L1b, EMB, m0, kz + 64, ar, tid);
  load64(Fwb, EMB, n0, kz + 64, br, tid);
  BAR();
  for (int k0 = 0; k0 < 384; k0 += 64) {
    const int cur = (k0 >> 6) & 1;
    const short* Ac = As[cur];
    const short* Bc = Bs[cur];
    GEMM_TILE_COMPUTE2(Ac, Bc, acc);
    if (k0 + 64 < 384) {
      write128(As[cur ^ 1], ar, tid);
      write64(Bs[cur ^ 1], br, tid);
      if (k0 + 128 < 384) {
        load128(L1b, EMB, m0, kz + k0 + 128, ar, tid);
        load64(Fwb, EMB, n0, kz + k0 + 128, br, tid);
      }
    }
    BAR();
  }
  float* P = Pp + (size_t)(u / 192) * (BS_TOK * EMB);
  const bool addb = (u / 192 == 0);
#pragma unroll
  for (int nt = 0; nt < 4; ++nt) {
    float bias = addb ? Fb[n0 + (nt << 4) + l15] : 0.0f;
#pragma unroll
    for (int uu = 0; uu < 2; ++uu)
#pragma unroll
      for (int r = 0; r < 4; ++r)
        P[(size_t)(m0 + (w << 5) + (uu << 4) + (quad << 2) + r) * EMB + n0 +
          (nt << 4) + l15] = acc[uu][nt][r] + bias;
  }
}

// ------------------------------------------------- phase: LN (wave-per-token)
__device__ void phase_ln(const float* __restrict__ Xa, const float* __restrict__ P,
                         const float* __restrict__ g, const float* __restrict__ bb,
                         float* __restrict__ Out, short* __restrict__ Outb,
                         int u, int tid) {
  const int NB = BS_TOK * EMB;
  const int wv = tid >> 6, lane = tid & 63;
  const int t = u * 4 + wv;
  const float* xa = Xa + (size_t)t * EMB;
  const float* p0 = P + (size_t)t * EMB;
  const float* p1 = p0 + NB;
  float4 v[3];
  float s = 0.f;
#pragma unroll
  for (int i = 0; i < 3; ++i) {
    int e = lane * 4 + i * 256;
    float4 a = *(const float4*)(xa + e);
    float4 b = *(const float4*)(p0 + e);
    float4 c = *(const float4*)(p1 + e);
    v[i].x = a.x + b.x + c.x;
    v[i].y = a.y + b.y + c.y;
    v[i].z = a.z + b.z + c.z;
    v[i].w = a.w + b.w + c.w;
    s += v[i].x + v[i].y + v[i].z + v[i].w;
  }
#pragma unroll
  for (int o = 32; o > 0; o >>= 1) s += __shfl_xor(s, o, 64);
  float mu = s * (1.0f / EMB);
  float q = 0.f;
#pragma unroll
  for (int i = 0; i < 3; ++i) {
    float dx = v[i].x - mu, dy = v[i].y - mu, dz = v[i].z - mu, dw = v[i].w - mu;
    q += dx * dx + dy * dy + dz * dz + dw * dw;
  }
#pragma unroll
  for (int o = 32; o > 0; o >>= 1) q += __shfl_xor(q, o, 64);
  float var = q * (1.0f / EMB);
  float r = rsqrtf(var + 1e-5f);
#pragma unroll
  for (int i = 0; i < 3; ++i) {
    int e = lane * 4 + i * 256;
    float4 gg = *(const float4*)(g + e);
    float4 bv = *(const float4*)(bb + e);
    float4 res;
    res.x = (v[i].x - mu) * r * gg.x + bv.x;
    res.y = (v[i].y - mu) * r * gg.y + bv.y;
    res.z = (v[i].z - mu) * r * gg.z + bv.z;
    res.w = (v[i].w - mu) * r * gg.w + bv.w;
    *(float4*)(Out + (size_t)t * EMB + e) = res;
    bf16x4 ob;
    ob[0] = f2bf(res.x);
    ob[1] = f2bf(res.y);
    ob[2] = f2bf(res.z);
    ob[3] = f2bf(res.w);
    *(bf16x4*)(Outb + (size_t)t * EMB + e) = ob;
  }
}

// ------------------------------------------------- persistent 13-layer kernel
__global__ __launch_bounds__(256, 2) void layers_kernel(
    const short* __restrict__ wqTb, const short* __restrict__ wob,
    const short* __restrict__ fwb, const float* __restrict__ g1,
    const float* __restrict__ b1, const float* __restrict__ fb,
    const float* __restrict__ g2, const float* __restrict__ b2,
    float* __restrict__ bufA, float* __restrict__ bufB, float* __restrict__ bufD,
    float* __restrict__ opart, float* __restrict__ Lpart,
    short* __restrict__ XbA, short* __restrict__ L1b,
    short* __restrict__ Qbf, short* __restrict__ Qtb,
    float* __restrict__ dOut, unsigned* __restrict__ barcnt) {
  __shared__ short sm[24576];  // 48 KB, reused per phase
  const int bid = blockIdx.x;
  const int tid = threadIdx.x;
  unsigned ph = 0;
  for (int it = 0; it < 13; ++it) {
    const int l = (it == 0) ? 0 : it - 1;  // layer 0 applied twice (faithful)
    phase_gemm_q(XbA, wqTb + (size_t)l * (NH * HD * EMB), Qbf, Qtb, bid, tid, sm);
    gridbar(barcnt, ph);
    phase_attn(Qbf, Qtb, opart, Lpart, bid, tid, sm);
    phase_attn(Qbf, Qtb, opart, Lpart, bid + NBLK, tid, sm);
    gridbar(barcnt, ph);
    phase_gemm_out(wob + (size_t)l * (EMB * EMB), opart, Lpart, bufB, bid, tid, sm);
    gridbar(barcnt, ph);
    phase_ln(bufA, bufB, g1 + l * EMB, b1 + l * EMB, bufD, L1b, bid, tid);
    if (bid < 128) phase_ln(bufA, bufB, g1 + l * EMB, b1 + l * EMB, bufD, L1b,
                            bid + NBLK, tid);
    gridbar(barcnt, ph);
    phase_ffn(L1b, fwb + (size_t)l * (EMB * EMB), fb + l * EMB, bufB, bid, tid, sm);
    gridbar(barcnt, ph);
    float* dst = (it == 12) ? dOut : bufA;
    phase_ln(bufD, bufB, g2 + l * EMB, b2 + l * EMB, dst, XbA, bid, tid);
    if (bid < 128) phase_ln(bufD, bufB, g2 + l * EMB, b2 + l * EMB, dst, XbA,
                            bid + NBLK, tid);
    if (it < 12) gridbar(barcnt, ph);
  }
}

extern "C" void kernel_launch(void* const* d_in, const int* in_sizes, int n_in,
                              void* d_out, int out_size, void* d_ws, size_t ws_size,
                              hipStream_t stream) {
  const float* tok = (const float*)d_in[0];
  const float* wq = (const float*)d_in[1];
  const float* wo = (const float*)d_in[2];
  const float* g1 = (const float*)d_in[3];
  const float* b1 = (const float*)d_in[4];
  const float* fw = (const float*)d_in[5];
  const float* fb = (const float*)d_in[6];
  const float* g2 = (const float*)d_in[7];
  const float* b2 = (const float*)d_in[8];
  const int NB = BS_TOK * EMB;  // 1572864 elems
  float* bufA = (float*)d_ws;         // X (residual, fp32)
  float* bufB = bufA + NB;            // gemm partials [2][NB]
  float* bufC = bufB + NB;            // (partial 1 of bufB span)
  float* bufD = bufC + NB;            // L1 fp32
  float* opart = bufD + NB;           // attn O partials [4][NB]
  short* XbA = (short*)(opart + 4 * (size_t)NB);  // bf16 of current X
  short* L1b = XbA + NB;              // bf16 of L1
  short* Qbf = L1b + NB;              // Q bf16 [H][2048][64]
  short* Qtb = Qbf + NB;              // Qt bf16 [H][64][2048]
  short* wqTb = Qtb + NB;             // wqT bf16 [L][H][64][768]
  short* wob = wqTb + WQN;            // wo bf16 [L][768][768]
  short* fwb = wob + WQN;             // fw bf16 [L][768][768]
  float* Lpart = (float*)(fwb + WQN); // [4][H][2048]
  unsigned* barcnt = (unsigned*)(Lpart + 4 * NH * BS_TOK);

  cvt_weights_kernel<<<dim3(WQN / (256 * 8), 2), 256, 0, stream>>>(wo, fw, wob, fwb);
  wq_trans_kernel<<<dim3(12, 12 * NH), 256, 0, stream>>>(wq, wqTb);
  pe_add_kernel<<<NB / 256, 256, 0, stream>>>(tok, bufA, XbA, barcnt);
  layers_kernel<<<NBLK, 256, 0, stream>>>(wqTb, wob, fwb, g1, b1, fb, g2, b2,
                                          bufA, bufB, bufD, opart, Lpart,
                                          XbA, L1b, Qbf, Qtb, (float*)d_out, barcnt);
}

// Round 6
// 2536.049 us; speedup vs baseline: 2.7381x; 2.7381x over previous
//
#include <hip/hip_runtime.h>
#include <hip/hip_bf16.h>

// BERT stack: L=12(+1 dup of layer0), H=12, E=768, D=64, B=4, S=512 -> BS=2048 tokens.
// Faithful bugs preserved:
//  - attention flattens batch: 2048 tokens attend to each other globally, q==k==v
//  - zc = z.reshape(768,2048) is a FLAT VIEW of z[H][N][D]  (no transpose)
//  - mh = (wo@zc).reshape(B,S,E) is a FLAT VIEW of mh_mat[768][2048]
//  - pe: p = 10000 for e<384 else 10001; even e -> sin, odd -> cos; s = t % 512
// R1-R3: inner-loop pipeline work, all NEUTRAL (1170->1161) => per-dispatch
// overhead dominates. R4/R5: persistent kernel, CORRECT (absmax 0.0625) but
// 6944us: single-counter atomic barrier = 384 contended RMWs + 768 threadfences
// per barrier ~ 85us x 77. Counters: MfmaUtil 1.5%, 95% idle => barrier-bound.
// R6: arrive/release barrier. Arrive = per-block OWN cacheline (RELEASE store,
// no RMW contention). Master block scans slots with 256 threads (RELAXED+sleep),
// one acquire fence, one RELEASE store to broadcast `release` word. Spinners
// RELAXED-poll release (read-only, no bouncing) + one acquire fence. One
// release/acquire pair per block per barrier == what a kernel boundary costs.

#define BS_TOK 2048
#define EMB 768
#define NH 12
#define HD 64
#define WQN (12 * NH * EMB * HD)  // elems per weight stack (7077888)
#define NBLK 384

typedef __attribute__((ext_vector_type(8))) short bf16x8;
typedef __attribute__((ext_vector_type(4))) short bf16x4;
typedef __attribute__((ext_vector_type(4))) float f32x4;

__device__ __forceinline__ short f2bf(float f) {
  union { __hip_bfloat16 h; short s; } u;
  u.h = __float2bfloat16(f);
  return u.s;
}

#define MFMA16(a, b, c) __builtin_amdgcn_mfma_f32_16x16x32_bf16(a, b, c, 0, 0, 0)
// XOR-swizzled LDS address for [r][k] tiles, 64-elem rows (zero-conflict)
#define SW64(r, k) ((r) * 64 + ((((k) >> 3) ^ ((r) & 7)) << 3) + ((k) & 7))
// Barrier that drains LDS ops only — in-flight global loads cross it.
#define BAR() asm volatile("s_waitcnt lgkmcnt(0)\n\ts_barrier" ::: "memory")

// ---- grid barrier: per-block arrive slots (64B apart) + master + release ----
// bar layout (unsigned): arrive[NBLK*16] (block b -> bar[b*16]), release at
// bar[NBLK*16]. Monotone phase counter; zeroed by pe_add each replay.
#define BAR_WORDS (NBLK * 16 + 16)
__device__ __forceinline__ void gridbar(unsigned* __restrict__ bar,
                                        unsigned ph, int bid, int tid) {
  unsigned* release = bar + NBLK * 16;
  __syncthreads();  // block's work done; vmem stores issued & complete
  if (bid == 0) {
    // master: 256 threads poll the 383 other slots in parallel
    if (tid > 0) {
      while (__hip_atomic_load(&bar[tid << 4], __ATOMIC_RELAXED,
                               __HIP_MEMORY_SCOPE_AGENT) < ph)
        __builtin_amdgcn_s_sleep(8);
    }
    if (tid < 128) {
      while (__hip_atomic_load(&bar[(tid + 256) << 4], __ATOMIC_RELAXED,
                               __HIP_MEMORY_SCOPE_AGENT) < ph)
        __builtin_amdgcn_s_sleep(8);
    }
    __syncthreads();
    if (tid == 0) {
      __builtin_amdgcn_fence(__ATOMIC_ACQUIRE, "agent");  // see all blocks' data
      __hip_atomic_store(release, ph, __ATOMIC_RELEASE,
                         __HIP_MEMORY_SCOPE_AGENT);        // publish
    }
    __syncthreads();
  } else {
    if (tid == 0) {
      __hip_atomic_store(&bar[bid << 4], ph, __ATOMIC_RELEASE,
                         __HIP_MEMORY_SCOPE_AGENT);        // arrive (own line)
      while (__hip_atomic_load(release, __ATOMIC_RELAXED,
                               __HIP_MEMORY_SCOPE_AGENT) < ph)
        __builtin_amdgcn_s_sleep(8);
      __builtin_amdgcn_fence(__ATOMIC_ACQUIRE, "agent");   // see others' data
    }
    __syncthreads();
  }
}

// ---------------------------------------------------------------- weight prep
__global__ __launch_bounds__(256) void cvt_weights_kernel(const float* __restrict__ wo,
                                                          const float* __restrict__ fw,
                                                          short* __restrict__ wob,
                                                          short* __restrict__ fwb) {
  const float* src = blockIdx.y ? fw : wo;
  short* dst = blockIdx.y ? fwb : wob;
  int i = (blockIdx.x * 256 + threadIdx.x) * 8;
  float4 a = *(const float4*)(src + i);
  float4 b = *(const float4*)(src + i + 4);
  bf16x8 t;
  t[0] = f2bf(a.x); t[1] = f2bf(a.y); t[2] = f2bf(a.z); t[3] = f2bf(a.w);
  t[4] = f2bf(b.x); t[5] = f2bf(b.y); t[6] = f2bf(b.z); t[7] = f2bf(b.w);
  *(bf16x8*)(dst + i) = t;
}

// wqT[l][h][d][e] <- wq[l][h][e][d], bf16
__global__ __launch_bounds__(256) void wq_trans_kernel(const float* __restrict__ wq,
                                                       short* __restrict__ wqT) {
  __shared__ short T[64 * 64];
  const int et = blockIdx.x;  // e-tile (12)
  const int lh = blockIdx.y;  // l*NH+h (144)
  const int tid = threadIdx.x;
  const float* src = wq + ((size_t)lh * EMB + et * 64) * HD;
  {
    int r = tid >> 2, c16 = (tid & 3) << 4;
    const float* p = src + r * HD + c16;
    float4 x0 = *(const float4*)(p + 0);
    float4 x1 = *(const float4*)(p + 4);
    float4 x2 = *(const float4*)(p + 8);
    float4 x3 = *(const float4*)(p + 12);
    bf16x8 a, b;
    a[0] = f2bf(x0.x); a[1] = f2bf(x0.y); a[2] = f2bf(x0.z); a[3] = f2bf(x0.w);
    a[4] = f2bf(x1.x); a[5] = f2bf(x1.y); a[6] = f2bf(x1.z); a[7] = f2bf(x1.w);
    b[0] = f2bf(x2.x); b[1] = f2bf(x2.y); b[2] = f2bf(x2.z); b[3] = f2bf(x2.w);
    b[4] = f2bf(x3.x); b[5] = f2bf(x3.y); b[6] = f2bf(x3.z); b[7] = f2bf(x3.w);
    int g = c16 >> 3;
    *(bf16x8*)&T[r * 64 + ((g ^ (r & 7)) << 3)] = a;
    *(bf16x8*)&T[r * 64 + (((g + 1) ^ (r & 7)) << 3)] = b;
  }
  __syncthreads();
  {
    int d = tid >> 2, e16 = (tid & 3) << 4;
    bf16x8 t0, t1;
#pragma unroll
    for (int j = 0; j < 8; ++j) t0[j] = T[SW64(e16 + j, d)];
#pragma unroll
    for (int j = 0; j < 8; ++j) t1[j] = T[SW64(e16 + 8 + j, d)];
    short* q = wqT + ((size_t)lh * HD + d) * EMB + et * 64 + e16;
    *(bf16x8*)(q) = t0;
    *(bf16x8*)(q + 8) = t1;
  }
}

// ------------------------------------------- pe + tokens (+ barrier region init)
__global__ __launch_bounds__(256) void pe_add_kernel(const float* __restrict__ tok,
                                                     float* __restrict__ X,
                                                     short* __restrict__ Xb,
                                                     unsigned* __restrict__ bar) {
  int idx = blockIdx.x * 256 + threadIdx.x;   // < 2048*768
  if (idx < BAR_WORDS) bar[idx] = 0;          // re-zero each graph replay
  int e = idx % EMB;
  int t = idx / EMB;
  int s = t & 511;                            // t = b*512 + s
  float p = (e < 384) ? 10000.0f : 10001.0f;  // 10000 XOR ((2e)//768)
  float ang = (float)s / p;
  float pe = (e & 1) ? cosf(ang) : sinf(ang);
  float v = tok[idx] + pe;
  X[idx] = v;
  Xb[idx] = f2bf(v);
}

// ---------------- staging helpers (split load/write for reg-prefetch pipeline)
__device__ __forceinline__ void load64(const short* __restrict__ src, int ld,
                                       int row0, int k0, bf16x8* r, int tid) {
  int rr = tid >> 2, kb = (tid & 3) << 4;
  const short* p = src + (size_t)(row0 + rr) * ld + k0 + kb;
  r[0] = *(const bf16x8*)(p);
  r[1] = *(const bf16x8*)(p + 8);
}
__device__ __forceinline__ void write64(short* dst, const bf16x8* r, int tid) {
  int rr = tid >> 2, g = (tid & 3) << 1;
  *(bf16x8*)&dst[rr * 64 + (((g + 0) ^ (rr & 7)) << 3)] = r[0];
  *(bf16x8*)&dst[rr * 64 + (((g + 1) ^ (rr & 7)) << 3)] = r[1];
}

__device__ __forceinline__ void load128(const short* __restrict__ src, int ld,
                                        int row0, int k0, bf16x8* r, int tid) {
  int rr = tid >> 1, kb = (tid & 1) << 5;
  const short* p = src + (size_t)(row0 + rr) * ld + k0 + kb;
  r[0] = *(const bf16x8*)(p);
  r[1] = *(const bf16x8*)(p + 8);
  r[2] = *(const bf16x8*)(p + 16);
  r[3] = *(const bf16x8*)(p + 24);
}
__device__ __forceinline__ void write128(short* dst, const bf16x8* r, int tid) {
  int rr = tid >> 1, g = (tid & 1) << 2;
#pragma unroll
  for (int i = 0; i < 4; ++i)
    *(bf16x8*)&dst[rr * 64 + (((g + i) ^ (rr & 7)) << 3)] = r[i];
}

// fused 4-way combine+transpose staging for gemm_out
__device__ __forceinline__ void load_comb(const float* __restrict__ Op,
                                          const float* __restrict__ Lp,
                                          int k0, int col0, float4 a[4][4],
                                          float& rl, int tid) {
  const int NB = BS_TOK * EMB;
  const int NHT = NH * BS_TOK;
  int kk = tid >> 2, nb = (tid & 3) << 4;
  size_t base = (size_t)(k0 + kk) * BS_TOK + col0 + nb;
  int hq = (int)(base >> 6);
  rl = 1.0f / ((Lp[hq] + Lp[hq + NHT]) + (Lp[hq + 2 * NHT] + Lp[hq + 3 * NHT]));
#pragma unroll
  for (int z = 0; z < 4; ++z)
#pragma unroll
    for (int q4 = 0; q4 < 4; ++q4)
      a[z][q4] = *(const float4*)(Op + base + (size_t)z * NB + q4 * 4);
}
__device__ __forceinline__ void write_comb(short* dst, const float4 a[4][4],
                                           float rl, int tid) {
  int kk = tid >> 2, nb = (tid & 3) << 4;
#pragma unroll
  for (int q4 = 0; q4 < 4; ++q4) {
    dst[SW64(nb + q4 * 4 + 0, kk)] =
        f2bf(((a[0][q4].x + a[1][q4].x) + (a[2][q4].x + a[3][q4].x)) * rl);
    dst[SW64(nb + q4 * 4 + 1, kk)] =
        f2bf(((a[0][q4].y + a[1][q4].y) + (a[2][q4].y + a[3][q4].y)) * rl);
    dst[SW64(nb + q4 * 4 + 2, kk)] =
        f2bf(((a[0][q4].z + a[1][q4].z) + (a[2][q4].z + a[3][q4].z)) * rl);
    dst[SW64(nb + q4 * 4 + 3, kk)] =
        f2bf(((a[0][q4].w + a[1][q4].w) + (a[2][q4].w + a[3][q4].w)) * rl);
  }
}

#define GEMM_TILE_COMPUTE(As, Bs, acc)                                              \
  {                                                                                 \
    _Pragma("unroll") for (int s = 0; s < 2; ++s) {                                 \
      int ra = (w << 4) + l15;                                                      \
      bf16x8 af = *(const bf16x8*)&As[ra * 64 + ((((s << 2) + quad) ^ (ra & 7)) << 3)]; \
      _Pragma("unroll") for (int nt = 0; nt < 4; ++nt) {                            \
        int rb = (nt << 4) + l15;                                                   \
        bf16x8 bf = *(const bf16x8*)&Bs[rb * 64 + ((((s << 2) + quad) ^ (rb & 7)) << 3)]; \
        acc[nt] = MFMA16(af, bf, acc[nt]);                                          \
      }                                                                             \
    }                                                                               \
  }

#define GEMM_TILE_COMPUTE2(As, Bs, acc)                                             \
  {                                                                                 \
    _Pragma("unroll") for (int s = 0; s < 2; ++s) {                                 \
      bf16x8 af[2];                                                                 \
      _Pragma("unroll") for (int u = 0; u < 2; ++u) {                               \
        int ra = (w << 5) + (u << 4) + l15;                                         \
        af[u] = *(const bf16x8*)&As[ra * 64 + ((((s << 2) + quad) ^ (ra & 7)) << 3)]; \
      }                                                                             \
      _Pragma("unroll") for (int nt = 0; nt < 4; ++nt) {                            \
        int rb = (nt << 4) + l15;                                                   \
        bf16x8 bf = *(const bf16x8*)&Bs[rb * 64 + ((((s << 2) + quad) ^ (rb & 7)) << 3)]; \
        acc[0][nt] = MFMA16(af[0], bf, acc[0][nt]);                                 \
        acc[1][nt] = MFMA16(af[1], bf, acc[1][nt]);                                 \
      }                                                                             \
    }                                                                               \
  }

// ------------------------------------------------- phase: Q = Xb * WqT
__device__ void phase_gemm_q(const short* __restrict__ Xb,
                             const short* __restrict__ WqT,
                             short* __restrict__ Qo, short* __restrict__ Qt,
                             int u, int tid, short* sm) {
  short* As[2] = {sm, sm + 4096};
  short* Bs[2] = {sm + 8192, sm + 12288};
  const int m0 = (u & 31) * 64;  // token tile
  const int h = u >> 5;          // head
  const int w = tid >> 6, lane = tid & 63, l15 = lane & 15, quad = lane >> 4;
  const short* wqh = WqT + (size_t)h * (HD * EMB);  // [d][e]
  f32x4 acc[4] = {};
  bf16x8 ar[2], br[2];
  load64(Xb, EMB, m0, 0, ar, tid);
  load64(wqh, EMB, 0, 0, br, tid);
  write64(As[0], ar, tid);
  write64(Bs[0], br, tid);
  load64(Xb, EMB, m0, 64, ar, tid);
  load64(wqh, EMB, 0, 64, br, tid);
  BAR();
  for (int k0 = 0; k0 < EMB; k0 += 64) {
    const int cur = (k0 >> 6) & 1;
    const short* Ac = As[cur];
    const short* Bc = Bs[cur];
    GEMM_TILE_COMPUTE(Ac, Bc, acc);
    if (k0 + 64 < EMB) {
      write64(As[cur ^ 1], ar, tid);
      write64(Bs[cur ^ 1], br, tid);
      if (k0 + 128 < EMB) {
        load64(Xb, EMB, m0, k0 + 128, ar, tid);
        load64(wqh, EMB, 0, k0 + 128, br, tid);
      }
    }
    BAR();
  }
  short* T = As[0];
#pragma unroll
  for (int nt = 0; nt < 4; ++nt)
#pragma unroll
    for (int r = 0; r < 4; ++r)
      T[SW64((w << 4) + (quad << 2) + r, (nt << 4) + l15)] = f2bf(acc[nt][r]);
  __syncthreads();
  {  // Qo[h][tok][d]
    int r2 = tid >> 2, kb = (tid & 3) << 4;
    int g = kb >> 3;
    bf16x8 q0v = *(const bf16x8*)&T[r2 * 64 + ((g ^ (r2 & 7)) << 3)];
    bf16x8 q1v = *(const bf16x8*)&T[r2 * 64 + (((g + 1) ^ (r2 & 7)) << 3)];
    short* qo = Qo + (size_t)h * (BS_TOK * HD) + (size_t)(m0 + r2) * HD + kb;
    *(bf16x8*)(qo) = q0v;
    *(bf16x8*)(qo + 8) = q1v;
  }
  {  // Qt[h][d][tok]
    int d = tid >> 2, tok0 = (tid & 3) << 4;
    bf16x8 t0, t1;
#pragma unroll
    for (int j = 0; j < 8; ++j) t0[j] = T[SW64(tok0 + j, d)];
#pragma unroll
    for (int j = 0; j < 8; ++j) t1[j] = T[SW64(tok0 + 8 + j, d)];
    short* qt = Qt + (size_t)h * (HD * BS_TOK) + (size_t)d * BS_TOK + m0 + tok0;
    *(bf16x8*)(qt) = t0;
    *(bf16x8*)(qt + 8) = t1;
  }
}

// ------------------------------------------------- phase: flash attention
__device__ void phase_attn(const short* __restrict__ Q,
                           const short* __restrict__ Qt,
                           float* __restrict__ Opart, float* __restrict__ Lpart,
                           int u, int tid, short* sm) {
  short* Ks[2] = {sm, sm + 4096};
  short* Vt[2] = {sm + 8192, sm + 12288};
  short* Pw = sm + 16384;
  const int h = (u >> 4) % NH;
  const int q0 = (u & 15) * 128;
  const int kt0 = (u / 192) * 8;  // 8 K-tiles per split
  const int lane = tid & 63;
  const int wv = tid >> 6;
  const int l15 = lane & 15;
  const int quad = lane >> 4;
  const short* Qh = Q + (size_t)h * (BS_TOK * HD);
  const short* Qth = Qt + (size_t)h * (HD * BS_TOK);
  short* myP = Pw + wv * 2048;

  bf16x8 qf[2][2];
#pragma unroll
  for (int sub = 0; sub < 2; ++sub) {
    const short* qp = Qh + (size_t)(q0 + wv * 32 + sub * 16 + l15) * HD + quad * 8;
    qf[sub][0] = *(const bf16x8*)(qp);
    qf[sub][1] = *(const bf16x8*)(qp + 32);
  }

  f32x4 o[2][4] = {};
  float lpl[2] = {0.f, 0.f};

  bf16x8 kreg[2], vreg[2];
#pragma unroll
  for (int i = 0; i < 2; ++i) {
    int c = i * 256 + tid;
    kreg[i] = *(const bf16x8*)(Qh + (size_t)kt0 * 4096 + c * 8);
    vreg[i] = *(const bf16x8*)(Qth + (size_t)(c >> 3) * BS_TOK + kt0 * 64 + (c & 7) * 8);
  }
#pragma unroll
  for (int i = 0; i < 2; ++i) {
    int c = i * 256 + tid, row = c >> 3, g = c & 7;
    *(bf16x8*)&Ks[0][row * 64 + ((g ^ (row & 7)) << 3)] = kreg[i];
    *(bf16x8*)&Vt[0][row * 64 + ((g ^ (row & 7)) << 3)] = vreg[i];
  }
#pragma unroll
  for (int i = 0; i < 2; ++i) {
    int c = i * 256 + tid;
    kreg[i] = *(const bf16x8*)(Qh + (size_t)(kt0 + 1) * 4096 + c * 8);
    vreg[i] = *(const bf16x8*)(Qth + (size_t)(c >> 3) * BS_TOK + (kt0 + 1) * 64 + (c & 7) * 8);
  }
  BAR();

  for (int kt = 0; kt < 8; ++kt) {
    const short* K_ = Ks[kt & 1];
    const short* V_ = Vt[kt & 1];

    f32x4 s[2][4];
    __builtin_amdgcn_s_setprio(1);
#pragma unroll
    for (int ct = 0; ct < 4; ++ct) {
      int row = ct * 16 + l15;
      bf16x8 kf0 = *(const bf16x8*)(&K_[row * 64 + ((quad ^ (row & 7)) << 3)]);
      bf16x8 kf1 = *(const bf16x8*)(&K_[row * 64 + (((4 + quad) ^ (row & 7)) << 3)]);
#pragma unroll
      for (int sub = 0; sub < 2; ++sub) {
        f32x4 a = (f32x4){0.f, 0.f, 0.f, 0.f};
        a = MFMA16(kf0, qf[sub][0], a);
        a = MFMA16(kf1, qf[sub][1], a);
        s[sub][ct] = a;
      }
    }
    __builtin_amdgcn_s_setprio(0);

#pragma unroll
    for (int sub = 0; sub < 2; ++sub) {
      int prow = sub * 16 + l15;
#pragma unroll
      for (int ct = 0; ct < 4; ++ct) {
        bf16x4 pv4;
#pragma unroll
        for (int r = 0; r < 4; ++r) {
          float p = exp2f(s[sub][ct][r] * 0.18033688011112042f);
          lpl[sub] += p;
          pv4[r] = f2bf(p);
        }
        int g = 2 * ct + (quad >> 1);
        *(bf16x4*)&myP[prow * 64 + ((g ^ (prow & 7)) << 3) + ((quad & 1) << 2)] = pv4;
      }
    }

    __builtin_amdgcn_s_setprio(1);
#pragma unroll
    for (int ks = 0; ks < 2; ++ks) {
      int c = ks * 4 + quad;
      bf16x8 pf0 = *(const bf16x8*)(&myP[l15 * 64 + ((c ^ (l15 & 7)) << 3)]);
      bf16x8 pf1 = *(const bf16x8*)(&myP[(16 + l15) * 64 + ((c ^ (l15 & 7)) << 3)]);
#pragma unroll
      for (int dt = 0; dt < 4; ++dt) {
        int row = dt * 16 + l15;
        bf16x8 vf = *(const bf16x8*)(&V_[row * 64 + ((c ^ (row & 7)) << 3)]);
        o[0][dt] = MFMA16(pf0, vf, o[0][dt]);
        o[1][dt] = MFMA16(pf1, vf, o[1][dt]);
      }
    }
    __builtin_amdgcn_s_setprio(0);

    if (kt + 1 < 8) {
      short* Kn = Ks[(kt & 1) ^ 1];
      short* Vn = Vt[(kt & 1) ^ 1];
#pragma unroll
      for (int i = 0; i < 2; ++i) {
        int c = i * 256 + tid, row = c >> 3, g = c & 7;
        *(bf16x8*)&Kn[row * 64 + ((g ^ (row & 7)) << 3)] = kreg[i];
        *(bf16x8*)&Vn[row * 64 + ((g ^ (row & 7)) << 3)] = vreg[i];
      }
      if (kt + 2 < 8) {
        int gt = kt0 + kt + 2;
#pragma unroll
        for (int i = 0; i < 2; ++i) {
          int c = i * 256 + tid;
          kreg[i] = *(const bf16x8*)(Qh + (size_t)gt * 4096 + c * 8);
          vreg[i] = *(const bf16x8*)(Qth + (size_t)(c >> 3) * BS_TOK + gt * 64 + (c & 7) * 8);
        }
      }
    }
    BAR();
  }

#pragma unroll
  for (int sub = 0; sub < 2; ++sub) {
    lpl[sub] += __shfl_xor(lpl[sub], 16, 64);
    lpl[sub] += __shfl_xor(lpl[sub], 32, 64);
  }

  const int NB = BS_TOK * EMB;
  const int z = u / 192;
  float* Oh = Opart + (size_t)z * NB + (size_t)h * (BS_TOK * HD);
  float* Lh = Lpart + ((size_t)z * NH + h) * BS_TOK;
  if (quad == 0) {
    Lh[q0 + wv * 32 + l15] = lpl[0];
    Lh[q0 + wv * 32 + 16 + l15] = lpl[1];
  }
#pragma unroll
  for (int sub = 0; sub < 2; ++sub)
#pragma unroll
    for (int r = 0; r < 4; ++r) {
      int qrow = q0 + wv * 32 + sub * 16 + quad * 4 + r;
#pragma unroll
      for (int dt = 0; dt < 4; ++dt)
        Oh[(size_t)qrow * HD + dt * 16 + l15] = o[sub][dt][r];
    }
}

// ------------------------------------------------- phase: MH = Wo * combine/l
__device__ void phase_gemm_out(const short* __restrict__ Wob,
                               const float* __restrict__ Op,
                               const float* __restrict__ Lp,
                               float* __restrict__ Pp,
                               int u, int tid, short* sm) {
  short* As[2] = {sm, sm + 8192};
  short* Bs[2] = {sm + 16384, sm + 20480};
  const int n0 = (u % 32) * 64;
  const int m0 = ((u / 32) % 6) * 128;
  const int kz = (u / 192) * 384;
  const int w = tid >> 6, lane = tid & 63, l15 = lane & 15, quad = lane >> 4;
  f32x4 acc[2][4] = {};
  bf16x8 ar[4];
  float4 ca[4][4];
  float rl;
  load128(Wob, EMB, m0, kz, ar, tid);
  load_comb(Op, Lp, kz, n0, ca, rl, tid);
  write128(As[0], ar, tid);
  write_comb(Bs[0], ca, rl, tid);
  load128(Wob, EMB, m0, kz + 64, ar, tid);
  load_comb(Op, Lp, kz + 64, n0, ca, rl, tid);
  BAR();
  for (int k0 = 0; k0 < 384; k0 += 64) {
    const int cur = (k0 >> 6) & 1;
    const short* Ac = As[cur];
    const short* Bc = Bs[cur];
    GEMM_TILE_COMPUTE2(Ac, Bc, acc);
    if (k0 + 64 < 384) {
      write128(As[cur ^ 1], ar, tid);
      write_comb(Bs[cur ^ 1], ca, rl, tid);
      if (k0 + 128 < 384) {
        load128(Wob, EMB, m0, kz + k0 + 128, ar, tid);
        load_comb(Op, Lp, kz + k0 + 128, n0, ca, rl, tid);
      }
    }
    BAR();
  }
  float* P = Pp + (size_t)(u / 192) * (BS_TOK * EMB);
#pragma unroll
  for (int uu = 0; uu < 2; ++uu)
#pragma unroll
    for (int nt = 0; nt < 4; ++nt)
#pragma unroll
      for (int r = 0; r < 4; ++r)
        P[(size_t)(m0 + (w << 5) + (uu << 4) + (quad << 2) + r) * BS_TOK + n0 +
          (nt << 4) + l15] = acc[uu][nt][r];
}

// ------------------------------------------------- phase: FFN
__device__ void phase_ffn(const short* __restrict__ L1b,
                          const short* __restrict__ Fwb,
                          const float* __restrict__ Fb,
                          float* __restrict__ Pp,
                          int u, int tid, short* sm) {
  short* As[2] = {sm, sm + 8192};
  short* Bs[2] = {sm + 16384, sm + 20480};
  const int m0 = (u % 16) * 128;
  const int n0 = ((u / 16) % 12) * 64;
  const int kz = (u / 192) * 384;
  const int w = tid >> 6, lane = tid & 63, l15 = lane & 15, quad = lane >> 4;
  f32x4 acc[2][4] = {};
  bf16x8 ar[4], br[2];
  load128(L1b, EMB, m0, kz, ar, tid);
  load64(Fwb, EMB, n0, kz, br, tid);
  write128(As[0], ar, tid);
  write64(Bs[0], br, tid);
  load128(L1b, EMB, m0, kz + 64, ar, tid);
  load64(Fwb, EMB, n0, kz + 64, br, tid);
  BAR();
  for (int k0 = 0; k0 < 384; k0 += 64) {
    const int cur = (k0 >> 6) & 1;
    const short* Ac = As[cur];
    const short* Bc = Bs[cur];
    GEMM_TILE_COMPUTE2(Ac, Bc, acc);
    if (k0 + 64 < 384) {
      write128(As[cur ^ 1], ar, tid);
      write64(Bs[cur ^ 1], br, tid);
      if (k0 + 128 < 384) {
        load128(L1b, EMB, m0, kz + k0 + 128, ar, tid);
        load64(Fwb, EMB, n0, kz + k0 + 128, br, tid);
      }
    }
    BAR();
  }
  float* P = Pp + (size_t)(u / 192) * (BS_TOK * EMB);
  const bool addb = (u / 192 == 0);
#pragma unroll
  for (int nt = 0; nt < 4; ++nt) {
    float bias = addb ? Fb[n0 + (nt << 4) + l15] : 0.0f;
#pragma unroll
    for (int uu = 0; uu < 2; ++uu)
#pragma unroll
      for (int r = 0; r < 4; ++r)
        P[(size_t)(m0 + (w << 5) + (uu << 4) + (quad << 2) + r) * EMB + n0 +
          (nt << 4) + l15] = acc[uu][nt][r] + bias;
  }
}

// ------------------------------------------------- phase: LN (wave-per-token)
__device__ void phase_ln(const float* __restrict__ Xa, const float* __restrict__ P,
                         const float* __restrict__ g, const float* __restrict__ bb,
                         float* __restrict__ Out, short* __restrict__ Outb,
                         int u, int tid) {
  const int NB = BS_TOK * EMB;
  const int wv = tid >> 6, lane = tid & 63;
  const int t = u * 4 + wv;
  const float* xa = Xa + (size_t)t * EMB;
  const float* p0 = P + (size_t)t * EMB;
  const float* p1 = p0 + NB;
  float4 v[3];
  float s = 0.f;
#pragma unroll
  for (int i = 0; i < 3; ++i) {
    int e = lane * 4 + i * 256;
    float4 a = *(const float4*)(xa + e);
    float4 b = *(const float4*)(p0 + e);
    float4 c = *(const float4*)(p1 + e);
    v[i].x = a.x + b.x + c.x;
    v[i].y = a.y + b.y + c.y;
    v[i].z = a.z + b.z + c.z;
    v[i].w = a.w + b.w + c.w;
    s += v[i].x + v[i].y + v[i].z + v[i].w;
  }
#pragma unroll
  for (int o = 32; o > 0; o >>= 1) s += __shfl_xor(s, o, 64);
  float mu = s * (1.0f / EMB);
  float q = 0.f;
#pragma unroll
  for (int i = 0; i < 3; ++i) {
    float dx = v[i].x - mu, dy = v[i].y - mu, dz = v[i].z - mu, dw = v[i].w - mu;
    q += dx * dx + dy * dy + dz * dz + dw * dw;
  }
#pragma unroll
  for (int o = 32; o > 0; o >>= 1) q += __shfl_xor(q, o, 64);
  float var = q * (1.0f / EMB);
  float r = rsqrtf(var + 1e-5f);
#pragma unroll
  for (int i = 0; i < 3; ++i) {
    int e = lane * 4 + i * 256;
    float4 gg = *(const float4*)(g + e);
    float4 bv = *(const float4*)(bb + e);
    float4 res;
    res.x = (v[i].x - mu) * r * gg.x + bv.x;
    res.y = (v[i].y - mu) * r * gg.y + bv.y;
    res.z = (v[i].z - mu) * r * gg.z + bv.z;
    res.w = (v[i].w - mu) * r * gg.w + bv.w;
    *(float4*)(Out + (size_t)t * EMB + e) = res;
    bf16x4 ob;
    ob[0] = f2bf(res.x);
    ob[1] = f2bf(res.y);
    ob[2] = f2bf(res.z);
    ob[3] = f2bf(res.w);
    *(bf16x4*)(Outb + (size_t)t * EMB + e) = ob;
  }
}

// ------------------------------------------------- persistent 13-layer kernel
__global__ __launch_bounds__(256, 2) void layers_kernel(
    const short* __restrict__ wqTb, const short* __restrict__ wob,
    const short* __restrict__ fwb, const float* __restrict__ g1,
    const float* __restrict__ b1, const float* __restrict__ fb,
    const float* __restrict__ g2, const float* __restrict__ b2,
    float* __restrict__ bufA, float* __restrict__ bufB, float* __restrict__ bufD,
    float* __restrict__ opart, float* __restrict__ Lpart,
    short* __restrict__ XbA, short* __restrict__ L1b,
    short* __restrict__ Qbf, short* __restrict__ Qtb,
    float* __restrict__ dOut, unsigned* __restrict__ bar) {
  __shared__ short sm[24576];  // 48 KB, reused per phase
  const int bid = blockIdx.x;
  const int tid = threadIdx.x;
  unsigned ph = 0;
  for (int it = 0; it < 13; ++it) {
    const int l = (it == 0) ? 0 : it - 1;  // layer 0 applied twice (faithful)
    phase_gemm_q(XbA, wqTb + (size_t)l * (NH * HD * EMB), Qbf, Qtb, bid, tid, sm);
    gridbar(bar, ++ph, bid, tid);
    phase_attn(Qbf, Qtb, opart, Lpart, bid, tid, sm);
    phase_attn(Qbf, Qtb, opart, Lpart, bid + NBLK, tid, sm);
    gridbar(bar, ++ph, bid, tid);
    phase_gemm_out(wob + (size_t)l * (EMB * EMB), opart, Lpart, bufB, bid, tid, sm);
    gridbar(bar, ++ph, bid, tid);
    phase_ln(bufA, bufB, g1 + l * EMB, b1 + l * EMB, bufD, L1b, bid, tid);
    if (bid < 128) phase_ln(bufA, bufB, g1 + l * EMB, b1 + l * EMB, bufD, L1b,
                            bid + NBLK, tid);
    gridbar(bar, ++ph, bid, tid);
    phase_ffn(L1b, fwb + (size_t)l * (EMB * EMB), fb + l * EMB, bufB, bid, tid, sm);
    gridbar(bar, ++ph, bid, tid);
    float* dst = (it == 12) ? dOut : bufA;
    phase_ln(bufD, bufB, g2 + l * EMB, b2 + l * EMB, dst, XbA, bid, tid);
    if (bid < 128) phase_ln(bufD, bufB, g2 + l * EMB, b2 + l * EMB, dst, XbA,
                            bid + NBLK, tid);
    if (it < 12) gridbar(bar, ++ph, bid, tid);
  }
}

extern "C" void kernel_launch(void* const* d_in, const int* in_sizes, int n_in,
                              void* d_out, int out_size, void* d_ws, size_t ws_size,
                              hipStream_t stream) {
  const float* tok = (const float*)d_in[0];
  const float* wq = (const float*)d_in[1];
  const float* wo = (const float*)d_in[2];
  const float* g1 = (const float*)d_in[3];
  const float* b1 = (const float*)d_in[4];
  const float* fw = (const float*)d_in[5];
  const float* fb = (const float*)d_in[6];
  const float* g2 = (const float*)d_in[7];
  const float* b2 = (const float*)d_in[8];
  const int NB = BS_TOK * EMB;  // 1572864 elems
  float* bufA = (float*)d_ws;         // X (residual, fp32)
  float* bufB = bufA + NB;            // gemm partials [2][NB]
  float* bufC = bufB + NB;            // (partial 1 of bufB span)
  float* bufD = bufC + NB;            // L1 fp32
  float* opart = bufD + NB;           // attn O partials [4][NB]
  short* XbA = (short*)(opart + 4 * (size_t)NB);  // bf16 of current X
  short* L1b = XbA + NB;              // bf16 of L1
  short* Qbf = L1b + NB;              // Q bf16 [H][2048][64]
  short* Qtb = Qbf + NB;              // Qt bf16 [H][64][2048]
  short* wqTb = Qtb + NB;             // wqT bf16 [L][H][64][768]
  short* wob = wqTb + WQN;            // wo bf16 [L][768][768]
  short* fwb = wob + WQN;             // fw bf16 [L][768][768]
  float* Lpart = (float*)(fwb + WQN); // [4][H][2048]
  unsigned* bar = (unsigned*)(Lpart + 4 * NH * BS_TOK);  // BAR_WORDS dwords

  cvt_weights_kernel<<<dim3(WQN / (256 * 8), 2), 256, 0, stream>>>(wo, fw, wob, fwb);
  wq_trans_kernel<<<dim3(12, 12 * NH), 256, 0, stream>>>(wq, wqTb);
  pe_add_kernel<<<NB / 256, 256, 0, stream>>>(tok, bufA, XbA, bar);
  layers_kernel<<<NBLK, 256, 0, stream>>>(wqTb, wob, fwb, g1, b1, fb, g2, b2,
                                          bufA, bufB, bufD, opart, Lpart,
                                          XbA, L1b, Qbf, Qtb, (float*)d_out, bar);
}

// Round 7
// 1199.243 us; speedup vs baseline: 5.7904x; 2.1147x over previous
//
#include <hip/hip_runtime.h>
#include <hip/hip_bf16.h>

// BERT stack: L=12(+1 dup of layer0), H=12, E=768, D=64, B=4, S=512 -> BS=2048 tokens.
// Faithful bugs preserved:
//  - attention flattens batch: 2048 tokens attend to each other globally, q==k==v
//  - zc = z.reshape(768,2048) is a FLAT VIEW of z[H][N][D]  (no transpose)
//  - mh = (wo@zc).reshape(B,S,E) is a FLAT VIEW of mh_mat[768][2048]
//  - pe: p = 10000 for e<384 else 10001; even e -> sin, odd -> cos; s = t % 512
// History: R1-R3 inner-loop opts NEUTRAL (1170->1161). R4-R6 persistent kernel:
// correct but software grid barrier ~17us/barrier >> HW dispatch boundary
// (~0.4us); measured WORK = ~1130us == multi-dispatch total. Dispatch overhead
// hypothesis REFUTED; back to multi-dispatch, attack work traffic.
// R7: attention ksplit=1 -> denominator completes in-block; attn writes final
// bf16 Z/l directly in flat-zc layout (contiguous 8KB per (h,q0) tile).
// Removes opart fp32 partials (24MB wr + 24MB rd + ~144MB L2 re-reads per
// layer) and Lpart; gemm_out B-staging reads bf16 rows.

#define BS_TOK 2048
#define EMB 768
#define NH 12
#define HD 64
#define WQN (12 * NH * EMB * HD)  // elems per weight stack (7077888)

typedef __attribute__((ext_vector_type(8))) short bf16x8;
typedef __attribute__((ext_vector_type(4))) short bf16x4;
typedef __attribute__((ext_vector_type(4))) float f32x4;

__device__ __forceinline__ short f2bf(float f) {
  union { __hip_bfloat16 h; short s; } u;
  u.h = __float2bfloat16(f);
  return u.s;
}

#define MFMA16(a, b, c) __builtin_amdgcn_mfma_f32_16x16x32_bf16(a, b, c, 0, 0, 0)
// XOR-swizzled LDS address for [r][k] tiles, 64-elem rows (zero-conflict)
#define SW64(r, k) ((r) * 64 + ((((k) >> 3) ^ ((r) & 7)) << 3) + ((k) & 7))
// Barrier that drains LDS ops only — in-flight global loads cross it.
#define BAR() asm volatile("s_waitcnt lgkmcnt(0)\n\ts_barrier" ::: "memory")

// ---------------------------------------------------------------- weight prep
__global__ __launch_bounds__(256) void cvt_weights_kernel(const float* __restrict__ wo,
                                                          const float* __restrict__ fw,
                                                          short* __restrict__ wob,
                                                          short* __restrict__ fwb) {
  const float* src = blockIdx.y ? fw : wo;
  short* dst = blockIdx.y ? fwb : wob;
  int i = (blockIdx.x * 256 + threadIdx.x) * 8;
  float4 a = *(const float4*)(src + i);
  float4 b = *(const float4*)(src + i + 4);
  bf16x8 t;
  t[0] = f2bf(a.x); t[1] = f2bf(a.y); t[2] = f2bf(a.z); t[3] = f2bf(a.w);
  t[4] = f2bf(b.x); t[5] = f2bf(b.y); t[6] = f2bf(b.z); t[7] = f2bf(b.w);
  *(bf16x8*)(dst + i) = t;
}

// wqT[l][h][d][e] <- wq[l][h][e][d], bf16
__global__ __launch_bounds__(256) void wq_trans_kernel(const float* __restrict__ wq,
                                                       short* __restrict__ wqT) {
  __shared__ short T[64 * 64];
  const int et = blockIdx.x;  // e-tile (12)
  const int lh = blockIdx.y;  // l*NH+h (144)
  const int tid = threadIdx.x;
  const float* src = wq + ((size_t)lh * EMB + et * 64) * HD;
  {
    int r = tid >> 2, c16 = (tid & 3) << 4;
    const float* p = src + r * HD + c16;
    float4 x0 = *(const float4*)(p + 0);
    float4 x1 = *(const float4*)(p + 4);
    float4 x2 = *(const float4*)(p + 8);
    float4 x3 = *(const float4*)(p + 12);
    bf16x8 a, b;
    a[0] = f2bf(x0.x); a[1] = f2bf(x0.y); a[2] = f2bf(x0.z); a[3] = f2bf(x0.w);
    a[4] = f2bf(x1.x); a[5] = f2bf(x1.y); a[6] = f2bf(x1.z); a[7] = f2bf(x1.w);
    b[0] = f2bf(x2.x); b[1] = f2bf(x2.y); b[2] = f2bf(x2.z); b[3] = f2bf(x2.w);
    b[4] = f2bf(x3.x); b[5] = f2bf(x3.y); b[6] = f2bf(x3.z); b[7] = f2bf(x3.w);
    int g = c16 >> 3;
    *(bf16x8*)&T[r * 64 + ((g ^ (r & 7)) << 3)] = a;
    *(bf16x8*)&T[r * 64 + (((g + 1) ^ (r & 7)) << 3)] = b;
  }
  __syncthreads();
  {
    int d = tid >> 2, e16 = (tid & 3) << 4;
    bf16x8 t0, t1;
#pragma unroll
    for (int j = 0; j < 8; ++j) t0[j] = T[SW64(e16 + j, d)];
#pragma unroll
    for (int j = 0; j < 8; ++j) t1[j] = T[SW64(e16 + 8 + j, d)];
    short* q = wqT + ((size_t)lh * HD + d) * EMB + et * 64 + e16;
    *(bf16x8*)(q) = t0;
    *(bf16x8*)(q + 8) = t1;
  }
}

// ---------------------------------------------------------------- pe + tokens
__global__ __launch_bounds__(256) void pe_add_kernel(const float* __restrict__ tok,
                                                     float* __restrict__ X,
                                                     short* __restrict__ Xb) {
  int idx = blockIdx.x * 256 + threadIdx.x;   // < 2048*768
  int e = idx % EMB;
  int t = idx / EMB;
  int s = t & 511;                            // t = b*512 + s
  float p = (e < 384) ? 10000.0f : 10001.0f;  // 10000 XOR ((2e)//768)
  float ang = (float)s / p;
  float pe = (e & 1) ? cosf(ang) : sinf(ang);
  float v = tok[idx] + pe;
  X[idx] = v;
  Xb[idx] = f2bf(v);
}

// ---------------- staging helpers (split load/write for reg-prefetch pipeline)
__device__ __forceinline__ void load64(const short* __restrict__ src, int ld,
                                       int row0, int k0, bf16x8* r, int tid) {
  int rr = tid >> 2, kb = (tid & 3) << 4;
  const short* p = src + (size_t)(row0 + rr) * ld + k0 + kb;
  r[0] = *(const bf16x8*)(p);
  r[1] = *(const bf16x8*)(p + 8);
}
__device__ __forceinline__ void write64(short* dst, const bf16x8* r, int tid) {
  int rr = tid >> 2, g = (tid & 3) << 1;
  *(bf16x8*)&dst[rr * 64 + (((g + 0) ^ (rr & 7)) << 3)] = r[0];
  *(bf16x8*)&dst[rr * 64 + (((g + 1) ^ (rr & 7)) << 3)] = r[1];
}

__device__ __forceinline__ void load128(const short* __restrict__ src, int ld,
                                        int row0, int k0, bf16x8* r, int tid) {
  int rr = tid >> 1, kb = (tid & 1) << 5;
  const short* p = src + (size_t)(row0 + rr) * ld + k0 + kb;
  r[0] = *(const bf16x8*)(p);
  r[1] = *(const bf16x8*)(p + 8);
  r[2] = *(const bf16x8*)(p + 16);
  r[3] = *(const bf16x8*)(p + 24);
}
__device__ __forceinline__ void write128(short* dst, const bf16x8* r, int tid) {
  int rr = tid >> 1, g = (tid & 1) << 2;
#pragma unroll
  for (int i = 0; i < 4; ++i)
    *(bf16x8*)&dst[rr * 64 + (((g + i) ^ (rr & 7)) << 3)] = r[i];
}

// B-staging for gemm_out from bf16 Zcb (flat [768][2048] row-major):
// dst[n][k] <- Zcb[(k0+k)*2048 + col0+n]  (transpose via swizzled LDS scatter)
__device__ __forceinline__ void load_zc(const short* __restrict__ Zcb,
                                        int k0, int col0, bf16x8 cr[2], int tid) {
  int kk = tid >> 2, nb = (tid & 3) << 4;
  const short* p = Zcb + (size_t)(k0 + kk) * BS_TOK + col0 + nb;
  cr[0] = *(const bf16x8*)(p);
  cr[1] = *(const bf16x8*)(p + 8);
}
__device__ __forceinline__ void write_zc(short* dst, const bf16x8 cr[2], int tid) {
  int kk = tid >> 2, nb = (tid & 3) << 4;
#pragma unroll
  for (int j = 0; j < 8; ++j) dst[SW64(nb + j, kk)] = cr[0][j];
#pragma unroll
  for (int j = 0; j < 8; ++j) dst[SW64(nb + 8 + j, kk)] = cr[1][j];
}

#define GEMM_TILE_COMPUTE(As, Bs, acc)                                              \
  {                                                                                 \
    _Pragma("unroll") for (int s = 0; s < 2; ++s) {                                 \
      int ra = (w << 4) + l15;                                                      \
      bf16x8 af = *(const bf16x8*)&As[ra * 64 + ((((s << 2) + quad) ^ (ra & 7)) << 3)]; \
      _Pragma("unroll") for (int nt = 0; nt < 4; ++nt) {                            \
        int rb = (nt << 4) + l15;                                                   \
        bf16x8 bf = *(const bf16x8*)&Bs[rb * 64 + ((((s << 2) + quad) ^ (rb & 7)) << 3)]; \
        acc[nt] = MFMA16(af, bf, acc[nt]);                                          \
      }                                                                             \
    }                                                                               \
  }

#define GEMM_TILE_COMPUTE2(As, Bs, acc)                                             \
  {                                                                                 \
    _Pragma("unroll") for (int s = 0; s < 2; ++s) {                                 \
      bf16x8 af[2];                                                                 \
      _Pragma("unroll") for (int u = 0; u < 2; ++u) {                               \
        int ra = (w << 5) + (u << 4) + l15;                                         \
        af[u] = *(const bf16x8*)&As[ra * 64 + ((((s << 2) + quad) ^ (ra & 7)) << 3)]; \
      }                                                                             \
      _Pragma("unroll") for (int nt = 0; nt < 4; ++nt) {                            \
        int rb = (nt << 4) + l15;                                                   \
        bf16x8 bf = *(const bf16x8*)&Bs[rb * 64 + ((((s << 2) + quad) ^ (rb & 7)) << 3)]; \
        acc[0][nt] = MFMA16(af[0], bf, acc[0][nt]);                                 \
        acc[1][nt] = MFMA16(af[1], bf, acc[1][nt]);                                 \
      }                                                                             \
    }                                                                               \
  }

// ------------------------------------------------- Q = Xb[2048x768] * WqT -> bf16 Q + Qt
__global__ __launch_bounds__(256) void gemm_q_kernel(const short* __restrict__ Xb,
                                                     const short* __restrict__ WqT,
                                                     short* __restrict__ Qo,
                                                     short* __restrict__ Qt) {
  __shared__ short As[2][64 * 64];
  __shared__ short Bs[2][64 * 64];
  const int m0 = blockIdx.x * 64;  // token tile
  const int h = blockIdx.y;        // head (N-tile of 64 = HD)
  const int tid = threadIdx.x;
  const int w = tid >> 6, lane = tid & 63, l15 = lane & 15, quad = lane >> 4;
  const short* wqh = WqT + (size_t)h * (HD * EMB);  // [d][e]
  f32x4 acc[4] = {};
  bf16x8 ar[2], br[2];
  load64(Xb, EMB, m0, 0, ar, tid);
  load64(wqh, EMB, 0, 0, br, tid);
  write64(As[0], ar, tid);
  write64(Bs[0], br, tid);
  load64(Xb, EMB, m0, 64, ar, tid);
  load64(wqh, EMB, 0, 64, br, tid);
  BAR();
  for (int k0 = 0; k0 < EMB; k0 += 64) {
    const int cur = (k0 >> 6) & 1;
    const short* Ac = As[cur];
    const short* Bc = Bs[cur];
    GEMM_TILE_COMPUTE(Ac, Bc, acc);
    if (k0 + 64 < EMB) {
      write64((short*)As[cur ^ 1], ar, tid);
      write64((short*)Bs[cur ^ 1], br, tid);
      if (k0 + 128 < EMB) {
        load64(Xb, EMB, m0, k0 + 128, ar, tid);
        load64(wqh, EMB, 0, k0 + 128, br, tid);
      }
    }
    BAR();
  }
  short* T = (short*)As[0];
#pragma unroll
  for (int nt = 0; nt < 4; ++nt)
#pragma unroll
    for (int r = 0; r < 4; ++r)
      T[SW64((w << 4) + (quad << 2) + r, (nt << 4) + l15)] = f2bf(acc[nt][r]);
  __syncthreads();
  {  // Qo[h][tok][d], coalesced b128 stores
    int r2 = tid >> 2, kb = (tid & 3) << 4;
    int g = kb >> 3;
    bf16x8 q0v = *(const bf16x8*)&T[r2 * 64 + ((g ^ (r2 & 7)) << 3)];
    bf16x8 q1v = *(const bf16x8*)&T[r2 * 64 + (((g + 1) ^ (r2 & 7)) << 3)];
    short* qo = Qo + (size_t)h * (BS_TOK * HD) + (size_t)(m0 + r2) * HD + kb;
    *(bf16x8*)(qo) = q0v;
    *(bf16x8*)(qo + 8) = q1v;
  }
  {  // Qt[h][d][tok], coalesced b128 stores
    int d = tid >> 2, tok0 = (tid & 3) << 4;
    bf16x8 t0, t1;
#pragma unroll
    for (int j = 0; j < 8; ++j) t0[j] = T[SW64(tok0 + j, d)];
#pragma unroll
    for (int j = 0; j < 8; ++j) t1[j] = T[SW64(tok0 + 8 + j, d)];
    short* qt = Qt + (size_t)h * (HD * BS_TOK) + (size_t)d * BS_TOK + m0 + tok0;
    *(bf16x8*)(qt) = t0;
    *(bf16x8*)(qt + 8) = t1;
  }
}

// ------------------------------------------------- flash attention, ksplit=1
// 256 thr (4 waves), Q-tile 64 (16 rows/wave), all 32 K-tiles per block.
// Denominator completes in-block -> writes final bf16 Z/l in flat-zc layout:
// tile (h,q0) = contiguous 8KB at Zcb + h*131072 + q0*64.
__global__ __launch_bounds__(256) void attn_mfma_kernel(const short* __restrict__ Q,
                                                        const short* __restrict__ Qt,
                                                        short* __restrict__ Zcb) {
  __shared__ short Ks[2][64 * 64];   // K[key][d]
  __shared__ short Vt[2][64 * 64];   // V^T[d][key]
  __shared__ short Pw[4][16 * 64];   // per-wave P[qrow][key]
  const int h = blockIdx.y;
  const int q0 = blockIdx.x * 64;
  const int tid = threadIdx.x;
  const int lane = tid & 63;
  const int wv = tid >> 6;
  const int l15 = lane & 15;
  const int quad = lane >> 4;
  const short* Qh = Q + (size_t)h * (BS_TOK * HD);
  const short* Qth = Qt + (size_t)h * (HD * BS_TOK);
  short* myP = Pw[wv];

  bf16x8 qf[2];
  {
    const short* qp = Qh + (size_t)(q0 + wv * 16 + l15) * HD + quad * 8;
    qf[0] = *(const bf16x8*)(qp);
    qf[1] = *(const bf16x8*)(qp + 32);
  }

  f32x4 o[4] = {};
  float lpl = 0.f;  // denominator partial for qrow = l15

  bf16x8 kreg[2], vreg[2];
#pragma unroll
  for (int i = 0; i < 2; ++i) {  // tile 0
    int c = i * 256 + tid;
    kreg[i] = *(const bf16x8*)(Qh + c * 8);
    vreg[i] = *(const bf16x8*)(Qth + (size_t)(c >> 3) * BS_TOK + (c & 7) * 8);
  }
#pragma unroll
  for (int i = 0; i < 2; ++i) {  // -> buf 0
    int c = i * 256 + tid, row = c >> 3, g = c & 7;
    *(bf16x8*)&Ks[0][row * 64 + ((g ^ (row & 7)) << 3)] = kreg[i];
    *(bf16x8*)&Vt[0][row * 64 + ((g ^ (row & 7)) << 3)] = vreg[i];
  }
#pragma unroll
  for (int i = 0; i < 2; ++i) {  // tile 1 in flight
    int c = i * 256 + tid;
    kreg[i] = *(const bf16x8*)(Qh + 4096 + c * 8);
    vreg[i] = *(const bf16x8*)(Qth + (size_t)(c >> 3) * BS_TOK + 64 + (c & 7) * 8);
  }
  BAR();

  for (int kt = 0; kt < 32; ++kt) {
    const short* K_ = Ks[kt & 1];
    const short* V_ = Vt[kt & 1];

    // S^T = K Q^T  (4 key-tiles of 16); lane: qrow=l15, key=ct*16+quad*4+r
    f32x4 s[4];
    __builtin_amdgcn_s_setprio(1);
#pragma unroll
    for (int ct = 0; ct < 4; ++ct) {
      f32x4 a = (f32x4){0.f, 0.f, 0.f, 0.f};
#pragma unroll
      for (int ks = 0; ks < 2; ++ks) {
        int row = ct * 16 + l15;
        int c = ks * 4 + quad;
        bf16x8 kf = *(const bf16x8*)(&K_[row * 64 + ((c ^ (row & 7)) << 3)]);
        a = MFMA16(kf, qf[ks], a);
      }
      s[ct] = a;
    }
    __builtin_amdgcn_s_setprio(0);

    // no-max softmax: p = exp(s/8) = exp2(s*0.125*log2e)
#pragma unroll
    for (int ct = 0; ct < 4; ++ct) {
      bf16x4 pv4;
#pragma unroll
      for (int r = 0; r < 4; ++r) {
        float p = exp2f(s[ct][r] * 0.18033688011112042f);
        lpl += p;
        pv4[r] = f2bf(p);
      }
      int g = 2 * ct + (quad >> 1);
      *(bf16x4*)&myP[l15 * 64 + ((g ^ (l15 & 7)) << 3) + ((quad & 1) << 2)] = pv4;
    }

    // O += P V  (wave-local myP; in-wave lgkmcnt ordering, no barrier)
    __builtin_amdgcn_s_setprio(1);
#pragma unroll
    for (int ks = 0; ks < 2; ++ks) {
      int c = ks * 4 + quad;
      bf16x8 pf = *(const bf16x8*)(&myP[l15 * 64 + ((c ^ (l15 & 7)) << 3)]);
#pragma unroll
      for (int dt = 0; dt < 4; ++dt) {
        int row = dt * 16 + l15;
        bf16x8 vf = *(const bf16x8*)(&V_[row * 64 + ((c ^ (row & 7)) << 3)]);
        o[dt] = MFMA16(pf, vf, o[dt]);
      }
    }
    __builtin_amdgcn_s_setprio(0);

    if (kt + 1 < 32) {  // publish next tile
      short* Kn = (short*)Ks[(kt & 1) ^ 1];
      short* Vn = (short*)Vt[(kt & 1) ^ 1];
#pragma unroll
      for (int i = 0; i < 2; ++i) {
        int c = i * 256 + tid, row = c >> 3, g = c & 7;
        *(bf16x8*)&Kn[row * 64 + ((g ^ (row & 7)) << 3)] = kreg[i];
        *(bf16x8*)&Vn[row * 64 + ((g ^ (row & 7)) << 3)] = vreg[i];
      }
      if (kt + 2 < 32) {
        int gt = kt + 2;
#pragma unroll
        for (int i = 0; i < 2; ++i) {
          int c = i * 256 + tid;
          kreg[i] = *(const bf16x8*)(Qh + (size_t)gt * 4096 + c * 8);
          vreg[i] = *(const bf16x8*)(Qth + (size_t)(c >> 3) * BS_TOK + gt * 64 + (c & 7) * 8);
        }
      }
    }
    BAR();
  }

  // full denominator per qrow=l15 (sum over quads), replicated across quads
  lpl += __shfl_xor(lpl, 16, 64);
  lpl += __shfl_xor(lpl, 32, 64);

  // per-output-row reciprocal: row quad*4+r's denom lives in lane l15=quad*4+r
  float rl[4];
#pragma unroll
  for (int r = 0; r < 4; ++r)
    rl[r] = 1.0f / __shfl(lpl, quad * 4 + r, 64);

  // stage bf16(o * 1/l) as [tok-local][d] tile, then ONE contiguous 8KB store
  short* T = (short*)Ks[0];  // K/V no longer needed after final BAR
#pragma unroll
  for (int dt = 0; dt < 4; ++dt)
#pragma unroll
    for (int r = 0; r < 4; ++r)
      T[SW64(wv * 16 + quad * 4 + r, dt * 16 + l15)] = f2bf(o[dt][r] * rl[r]);
  __syncthreads();
  {
    // Zc flat: z[h][n][d] at h*131072 + n*64 + d -> this tile is contiguous
    short* zo = Zcb + (size_t)h * (BS_TOK * HD) + (size_t)q0 * HD;
    int r2 = tid >> 2, kb = (tid & 3) << 4;
    int g = kb >> 3;
    bf16x8 z0 = *(const bf16x8*)&T[r2 * 64 + ((g ^ (r2 & 7)) << 3)];
    bf16x8 z1 = *(const bf16x8*)&T[r2 * 64 + (((g + 1) ^ (r2 & 7)) << 3)];
    *(bf16x8*)(zo + r2 * 64 + kb) = z0;
    *(bf16x8*)(zo + r2 * 64 + kb + 8) = z1;
  }
}

// ------------------------------------------------- MH = Wo * Zc (bf16), 128x64, ksplit=2
__global__ __launch_bounds__(256) void gemm_out_kernel(const short* __restrict__ Wob,
                                                       const short* __restrict__ Zcb,
                                                       float* __restrict__ Pp) {
  __shared__ short As[2][128 * 64];
  __shared__ short Bs[2][64 * 64];
  const int n0 = blockIdx.x * 64;   // j cols (2048 -> 32)
  const int m0 = blockIdx.y * 128;  // e rows (768 -> 6)
  const int kz = blockIdx.z * 384;  // K half
  const int tid = threadIdx.x;
  const int w = tid >> 6, lane = tid & 63, l15 = lane & 15, quad = lane >> 4;
  f32x4 acc[2][4] = {};
  bf16x8 ar[4], cr[2];
  load128(Wob, EMB, m0, kz, ar, tid);
  load_zc(Zcb, kz, n0, cr, tid);
  write128((short*)As[0], ar, tid);
  write_zc((short*)Bs[0], cr, tid);
  load128(Wob, EMB, m0, kz + 64, ar, tid);
  load_zc(Zcb, kz + 64, n0, cr, tid);
  BAR();
  for (int k0 = 0; k0 < 384; k0 += 64) {
    const int cur = (k0 >> 6) & 1;
    const short* Ac = As[cur];
    const short* Bc = Bs[cur];
    GEMM_TILE_COMPUTE2(Ac, Bc, acc);
    if (k0 + 64 < 384) {
      write128((short*)As[cur ^ 1], ar, tid);
      write_zc((short*)Bs[cur ^ 1], cr, tid);
      if (k0 + 128 < 384) {
        load128(Wob, EMB, m0, kz + k0 + 128, ar, tid);
        load_zc(Zcb, kz + k0 + 128, n0, cr, tid);
      }
    }
    BAR();
  }
  float* P = Pp + (size_t)blockIdx.z * (BS_TOK * EMB);
#pragma unroll
  for (int u = 0; u < 2; ++u)
#pragma unroll
    for (int nt = 0; nt < 4; ++nt)
#pragma unroll
      for (int r = 0; r < 4; ++r)
        P[(size_t)(m0 + (w << 5) + (u << 4) + (quad << 2) + r) * BS_TOK + n0 +
          (nt << 4) + l15] = acc[u][nt][r];
}

// ------------------------------------------------- FFN = L1b * fwb^T + fb, 128x64, ksplit=2
__global__ __launch_bounds__(256) void gemm_ffn_kernel(const short* __restrict__ L1b,
                                                       const short* __restrict__ Fwb,
                                                       const float* __restrict__ Fb,
                                                       float* __restrict__ Pp) {
  __shared__ short As[2][128 * 64];
  __shared__ short Bs[2][64 * 64];
  const int m0 = blockIdx.x * 128;  // token tile (16)
  const int n0 = blockIdx.y * 64;   // out-feature tile (12)
  const int kz = blockIdx.z * 384;  // K half
  const int tid = threadIdx.x;
  const int w = tid >> 6, lane = tid & 63, l15 = lane & 15, quad = lane >> 4;
  f32x4 acc[2][4] = {};
  bf16x8 ar[4], br[2];
  load128(L1b, EMB, m0, kz, ar, tid);
  load64(Fwb, EMB, n0, kz, br, tid);
  write128((short*)As[0], ar, tid);
  write64((short*)Bs[0], br, tid);
  load128(L1b, EMB, m0, kz + 64, ar, tid);
  load64(Fwb, EMB, n0, kz + 64, br, tid);
  BAR();
  for (int k0 = 0; k0 < 384; k0 += 64) {
    const int cur = (k0 >> 6) & 1;
    const short* Ac = As[cur];
    const short* Bc = Bs[cur];
    GEMM_TILE_COMPUTE2(Ac, Bc, acc);
    if (k0 + 64 < 384) {
      write128((short*)As[cur ^ 1], ar, tid);
      write64((short*)Bs[cur ^ 1], br, tid);
      if (k0 + 128 < 384) {
        load128(L1b, EMB, m0, kz + k0 + 128, ar, tid);
        load64(Fwb, EMB, n0, kz + k0 + 128, br, tid);
      }
    }
    BAR();
  }
  float* P = Pp + (size_t)blockIdx.z * (BS_TOK * EMB);
  const bool addb = (blockIdx.z == 0);
#pragma unroll
  for (int nt = 0; nt < 4; ++nt) {
    float bias = addb ? Fb[n0 + (nt << 4) + l15] : 0.0f;
#pragma unroll
    for (int u = 0; u < 2; ++u)
#pragma unroll
      for (int r = 0; r < 4; ++r)
        P[(size_t)(m0 + (w << 5) + (u << 4) + (quad << 2) + r) * EMB + n0 +
          (nt << 4) + l15] = acc[u][nt][r] + bias;
  }
}

// ------------------------------------------------- LN(Xa + P0 + P1) -> fp32 + bf16
// Wave-per-token: 4 tokens/block, shuffle-only reductions, no LDS/barriers.
__global__ __launch_bounds__(256) void ln_kernel(const float* __restrict__ Xa,
                                                 const float* __restrict__ P,
                                                 const float* __restrict__ g,
                                                 const float* __restrict__ bb,
                                                 float* __restrict__ Out,
                                                 short* __restrict__ Outb) {
  const int NB = BS_TOK * EMB;
  const int wv = threadIdx.x >> 6, lane = threadIdx.x & 63;
  const int t = blockIdx.x * 4 + wv;
  const float* xa = Xa + (size_t)t * EMB;
  const float* p0 = P + (size_t)t * EMB;
  const float* p1 = p0 + NB;
  float4 v[3];
  float s = 0.f;
#pragma unroll
  for (int i = 0; i < 3; ++i) {
    int e = lane * 4 + i * 256;
    float4 a = *(const float4*)(xa + e);
    float4 b = *(const float4*)(p0 + e);
    float4 c = *(const float4*)(p1 + e);
    v[i].x = a.x + b.x + c.x;
    v[i].y = a.y + b.y + c.y;
    v[i].z = a.z + b.z + c.z;
    v[i].w = a.w + b.w + c.w;
    s += v[i].x + v[i].y + v[i].z + v[i].w;
  }
#pragma unroll
  for (int o = 32; o > 0; o >>= 1) s += __shfl_xor(s, o, 64);
  float mu = s * (1.0f / EMB);
  float q = 0.f;
#pragma unroll
  for (int i = 0; i < 3; ++i) {
    float dx = v[i].x - mu, dy = v[i].y - mu, dz = v[i].z - mu, dw = v[i].w - mu;
    q += dx * dx + dy * dy + dz * dz + dw * dw;
  }
#pragma unroll
  for (int o = 32; o > 0; o >>= 1) q += __shfl_xor(q, o, 64);
  float var = q * (1.0f / EMB);
  float r = rsqrtf(var + 1e-5f);
#pragma unroll
  for (int i = 0; i < 3; ++i) {
    int e = lane * 4 + i * 256;
    float4 gg = *(const float4*)(g + e);
    float4 bv = *(const float4*)(bb + e);
    float4 res;
    res.x = (v[i].x - mu) * r * gg.x + bv.x;
    res.y = (v[i].y - mu) * r * gg.y + bv.y;
    res.z = (v[i].z - mu) * r * gg.z + bv.z;
    res.w = (v[i].w - mu) * r * gg.w + bv.w;
    *(float4*)(Out + (size_t)t * EMB + e) = res;
    bf16x4 ob;
    ob[0] = f2bf(res.x);
    ob[1] = f2bf(res.y);
    ob[2] = f2bf(res.z);
    ob[3] = f2bf(res.w);
    *(bf16x4*)(Outb + (size_t)t * EMB + e) = ob;
  }
}

extern "C" void kernel_launch(void* const* d_in, const int* in_sizes, int n_in,
                              void* d_out, int out_size, void* d_ws, size_t ws_size,
                              hipStream_t stream) {
  const float* tok = (const float*)d_in[0];
  const float* wq = (const float*)d_in[1];
  const float* wo = (const float*)d_in[2];
  const float* g1 = (const float*)d_in[3];
  const float* b1 = (const float*)d_in[4];
  const float* fw = (const float*)d_in[5];
  const float* fb = (const float*)d_in[6];
  const float* g2 = (const float*)d_in[7];
  const float* b2 = (const float*)d_in[8];
  const int NB = BS_TOK * EMB;  // 1572864 elems
  float* bufA = (float*)d_ws;        // X (residual, fp32)
  float* bufB = bufA + NB;           // gemm partial 0
  float* bufC = bufB + NB;           // gemm partial 1
  float* bufD = bufC + NB;           // L1 fp32
  short* XbA = (short*)(bufD + NB);  // bf16 of current X
  short* L1b = XbA + NB;             // bf16 of L1
  short* Qbf = L1b + NB;             // Q bf16 [H][2048][64]
  short* Qtb = Qbf + NB;             // Qt bf16 [H][64][2048]
  short* Zcb = Qtb + NB;             // attn out bf16, flat zc [768][2048]
  short* wqTb = Zcb + NB;            // wqT bf16 [L][H][64][768]
  short* wob = wqTb + WQN;           // wo bf16 [L][768][768]
  short* fwb = wob + WQN;            // fw bf16 [L][768][768]

  cvt_weights_kernel<<<dim3(WQN / (256 * 8), 2), 256, 0, stream>>>(wo, fw, wob, fwb);
  wq_trans_kernel<<<dim3(12, 12 * NH), 256, 0, stream>>>(wq, wqTb);
  pe_add_kernel<<<NB / 256, 256, 0, stream>>>(tok, bufA, XbA);
  for (int it = 0; it < 13; ++it) {
    int l = (it == 0) ? 0 : it - 1;  // layer 0 applied twice (faithful)
    gemm_q_kernel<<<dim3(32, NH), 256, 0, stream>>>(
        XbA, wqTb + (size_t)l * (NH * HD * EMB), Qbf, Qtb);
    attn_mfma_kernel<<<dim3(32, NH), 256, 0, stream>>>(Qbf, Qtb, Zcb);
    gemm_out_kernel<<<dim3(32, 6, 2), 256, 0, stream>>>(
        wob + (size_t)l * (EMB * EMB), Zcb, bufB);
    ln_kernel<<<BS_TOK / 4, 256, 0, stream>>>(bufA, bufB, g1 + l * EMB, b1 + l * EMB,
                                              bufD, L1b);
    gemm_ffn_kernel<<<dim3(16, 12, 2), 256, 0, stream>>>(
        L1b, fwb + (size_t)l * (EMB * EMB), fb + l * EMB, bufB);
    float* ln2_dst = (it == 12) ? (float*)d_out : bufA;
    ln_kernel<<<BS_TOK / 4, 256, 0, stream>>>(bufD, bufB, g2 + l * EMB, b2 + l * EMB,
                                              ln2_dst, XbA);
  }
}

// Round 8
// 1178.917 us; speedup vs baseline: 5.8902x; 1.0172x over previous
//
#include <hip/hip_runtime.h>
#include <hip/hip_bf16.h>

// BERT stack: L=12(+1 dup of layer0), H=12, E=768, D=64, B=4, S=512 -> BS=2048 tokens.
// Faithful bugs preserved:
//  - attention flattens batch: 2048 tokens attend to each other globally, q==k==v
//  - zc = z.reshape(768,2048) is a FLAT VIEW of z[H][N][D]  (no transpose)
//  - mh = (wo@zc).reshape(B,S,E) is a FLAT VIEW of mh_mat[768][2048]
//  - pe: p = 10000 for e<384 else 10001; even e -> sin, odd -> cos; s = t % 512
// History: R1-R3 inner-loop opts NEUTRAL; R4-R6 persistent kernel refuted
// (software grid barrier 17us >> HW dispatch ~0.4us). R7 profile: attn = 578us
// (48%) at MfmaUtil 10% / VALUBusy 38% / occ 12% -> ~3300 cyc/tile vs ~600 of
// issue work = latency-stall-bound at ~1 wave/SIMD.
// R8: attention paired K-tiles (quad-buffered K/V, 2 P-regions/wave, 80KB LDS):
// two independent QK^T->softmax->PV chains per barrier (16 BARs vs 32); tile
// B's MFMAs overlap tile A's softmax VALU + ds_read latency. Staged LDS writes
// moved before compute (overlap); denominator adds pairwise-treed.

#define BS_TOK 2048
#define EMB 768
#define NH 12
#define HD 64
#define WQN (12 * NH * EMB * HD)  // elems per weight stack (7077888)

typedef __attribute__((ext_vector_type(8))) short bf16x8;
typedef __attribute__((ext_vector_type(4))) short bf16x4;
typedef __attribute__((ext_vector_type(4))) float f32x4;

__device__ __forceinline__ short f2bf(float f) {
  union { __hip_bfloat16 h; short s; } u;
  u.h = __float2bfloat16(f);
  return u.s;
}

#define MFMA16(a, b, c) __builtin_amdgcn_mfma_f32_16x16x32_bf16(a, b, c, 0, 0, 0)
// XOR-swizzled LDS address for [r][k] tiles, 64-elem rows (zero-conflict)
#define SW64(r, k) ((r) * 64 + ((((k) >> 3) ^ ((r) & 7)) << 3) + ((k) & 7))
// Barrier that drains LDS ops only — in-flight global loads cross it.
#define BAR() asm volatile("s_waitcnt lgkmcnt(0)\n\ts_barrier" ::: "memory")

// ---------------------------------------------------------------- weight prep
__global__ __launch_bounds__(256) void cvt_weights_kernel(const float* __restrict__ wo,
                                                          const float* __restrict__ fw,
                                                          short* __restrict__ wob,
                                                          short* __restrict__ fwb) {
  const float* src = blockIdx.y ? fw : wo;
  short* dst = blockIdx.y ? fwb : wob;
  int i = (blockIdx.x * 256 + threadIdx.x) * 8;
  float4 a = *(const float4*)(src + i);
  float4 b = *(const float4*)(src + i + 4);
  bf16x8 t;
  t[0] = f2bf(a.x); t[1] = f2bf(a.y); t[2] = f2bf(a.z); t[3] = f2bf(a.w);
  t[4] = f2bf(b.x); t[5] = f2bf(b.y); t[6] = f2bf(b.z); t[7] = f2bf(b.w);
  *(bf16x8*)(dst + i) = t;
}

// wqT[l][h][d][e] <- wq[l][h][e][d], bf16
__global__ __launch_bounds__(256) void wq_trans_kernel(const float* __restrict__ wq,
                                                       short* __restrict__ wqT) {
  __shared__ short T[64 * 64];
  const int et = blockIdx.x;  // e-tile (12)
  const int lh = blockIdx.y;  // l*NH+h (144)
  const int tid = threadIdx.x;
  const float* src = wq + ((size_t)lh * EMB + et * 64) * HD;
  {
    int r = tid >> 2, c16 = (tid & 3) << 4;
    const float* p = src + r * HD + c16;
    float4 x0 = *(const float4*)(p + 0);
    float4 x1 = *(const float4*)(p + 4);
    float4 x2 = *(const float4*)(p + 8);
    float4 x3 = *(const float4*)(p + 12);
    bf16x8 a, b;
    a[0] = f2bf(x0.x); a[1] = f2bf(x0.y); a[2] = f2bf(x0.z); a[3] = f2bf(x0.w);
    a[4] = f2bf(x1.x); a[5] = f2bf(x1.y); a[6] = f2bf(x1.z); a[7] = f2bf(x1.w);
    b[0] = f2bf(x2.x); b[1] = f2bf(x2.y); b[2] = f2bf(x2.z); b[3] = f2bf(x2.w);
    b[4] = f2bf(x3.x); b[5] = f2bf(x3.y); b[6] = f2bf(x3.z); b[7] = f2bf(x3.w);
    int g = c16 >> 3;
    *(bf16x8*)&T[r * 64 + ((g ^ (r & 7)) << 3)] = a;
    *(bf16x8*)&T[r * 64 + (((g + 1) ^ (r & 7)) << 3)] = b;
  }
  __syncthreads();
  {
    int d = tid >> 2, e16 = (tid & 3) << 4;
    bf16x8 t0, t1;
#pragma unroll
    for (int j = 0; j < 8; ++j) t0[j] = T[SW64(e16 + j, d)];
#pragma unroll
    for (int j = 0; j < 8; ++j) t1[j] = T[SW64(e16 + 8 + j, d)];
    short* q = wqT + ((size_t)lh * HD + d) * EMB + et * 64 + e16;
    *(bf16x8*)(q) = t0;
    *(bf16x8*)(q + 8) = t1;
  }
}

// ---------------------------------------------------------------- pe + tokens
__global__ __launch_bounds__(256) void pe_add_kernel(const float* __restrict__ tok,
                                                     float* __restrict__ X,
                                                     short* __restrict__ Xb) {
  int idx = blockIdx.x * 256 + threadIdx.x;   // < 2048*768
  int e = idx % EMB;
  int t = idx / EMB;
  int s = t & 511;                            // t = b*512 + s
  float p = (e < 384) ? 10000.0f : 10001.0f;  // 10000 XOR ((2e)//768)
  float ang = (float)s / p;
  float pe = (e & 1) ? cosf(ang) : sinf(ang);
  float v = tok[idx] + pe;
  X[idx] = v;
  Xb[idx] = f2bf(v);
}

// ---------------- staging helpers (split load/write for reg-prefetch pipeline)
__device__ __forceinline__ void load64(const short* __restrict__ src, int ld,
                                       int row0, int k0, bf16x8* r, int tid) {
  int rr = tid >> 2, kb = (tid & 3) << 4;
  const short* p = src + (size_t)(row0 + rr) * ld + k0 + kb;
  r[0] = *(const bf16x8*)(p);
  r[1] = *(const bf16x8*)(p + 8);
}
__device__ __forceinline__ void write64(short* dst, const bf16x8* r, int tid) {
  int rr = tid >> 2, g = (tid & 3) << 1;
  *(bf16x8*)&dst[rr * 64 + (((g + 0) ^ (rr & 7)) << 3)] = r[0];
  *(bf16x8*)&dst[rr * 64 + (((g + 1) ^ (rr & 7)) << 3)] = r[1];
}

__device__ __forceinline__ void load128(const short* __restrict__ src, int ld,
                                        int row0, int k0, bf16x8* r, int tid) {
  int rr = tid >> 1, kb = (tid & 1) << 5;
  const short* p = src + (size_t)(row0 + rr) * ld + k0 + kb;
  r[0] = *(const bf16x8*)(p);
  r[1] = *(const bf16x8*)(p + 8);
  r[2] = *(const bf16x8*)(p + 16);
  r[3] = *(const bf16x8*)(p + 24);
}
__device__ __forceinline__ void write128(short* dst, const bf16x8* r, int tid) {
  int rr = tid >> 1, g = (tid & 1) << 2;
#pragma unroll
  for (int i = 0; i < 4; ++i)
    *(bf16x8*)&dst[rr * 64 + (((g + i) ^ (rr & 7)) << 3)] = r[i];
}

// B-staging for gemm_out from bf16 Zcb (flat [768][2048] row-major):
// dst[n][k] <- Zcb[(k0+k)*2048 + col0+n]  (transpose via swizzled LDS scatter)
__device__ __forceinline__ void load_zc(const short* __restrict__ Zcb,
                                        int k0, int col0, bf16x8 cr[2], int tid) {
  int kk = tid >> 2, nb = (tid & 3) << 4;
  const short* p = Zcb + (size_t)(k0 + kk) * BS_TOK + col0 + nb;
  cr[0] = *(const bf16x8*)(p);
  cr[1] = *(const bf16x8*)(p + 8);
}
__device__ __forceinline__ void write_zc(short* dst, const bf16x8 cr[2], int tid) {
  int kk = tid >> 2, nb = (tid & 3) << 4;
#pragma unroll
  for (int j = 0; j < 8; ++j) dst[SW64(nb + j, kk)] = cr[0][j];
#pragma unroll
  for (int j = 0; j < 8; ++j) dst[SW64(nb + 8 + j, kk)] = cr[1][j];
}

#define GEMM_TILE_COMPUTE(As, Bs, acc)                                              \
  {                                                                                 \
    _Pragma("unroll") for (int s = 0; s < 2; ++s) {                                 \
      int ra = (w << 4) + l15;                                                      \
      bf16x8 af = *(const bf16x8*)&As[ra * 64 + ((((s << 2) + quad) ^ (ra & 7)) << 3)]; \
      _Pragma("unroll") for (int nt = 0; nt < 4; ++nt) {                            \
        int rb = (nt << 4) + l15;                                                   \
        bf16x8 bf = *(const bf16x8*)&Bs[rb * 64 + ((((s << 2) + quad) ^ (rb & 7)) << 3)]; \
        acc[nt] = MFMA16(af, bf, acc[nt]);                                          \
      }                                                                             \
    }                                                                               \
  }

#define GEMM_TILE_COMPUTE2(As, Bs, acc)                                             \
  {                                                                                 \
    _Pragma("unroll") for (int s = 0; s < 2; ++s) {                                 \
      bf16x8 af[2];                                                                 \
      _Pragma("unroll") for (int u = 0; u < 2; ++u) {                               \
        int ra = (w << 5) + (u << 4) + l15;                                         \
        af[u] = *(const bf16x8*)&As[ra * 64 + ((((s << 2) + quad) ^ (ra & 7)) << 3)]; \
      }                                                                             \
      _Pragma("unroll") for (int nt = 0; nt < 4; ++nt) {                            \
        int rb = (nt << 4) + l15;                                                   \
        bf16x8 bf = *(const bf16x8*)&Bs[rb * 64 + ((((s << 2) + quad) ^ (rb & 7)) << 3)]; \
        acc[0][nt] = MFMA16(af[0], bf, acc[0][nt]);                                 \
        acc[1][nt] = MFMA16(af[1], bf, acc[1][nt]);                                 \
      }                                                                             \
    }                                                                               \
  }

// ------------------------------------------------- Q = Xb[2048x768] * WqT -> bf16 Q + Qt
__global__ __launch_bounds__(256) void gemm_q_kernel(const short* __restrict__ Xb,
                                                     const short* __restrict__ WqT,
                                                     short* __restrict__ Qo,
                                                     short* __restrict__ Qt) {
  __shared__ short As[2][64 * 64];
  __shared__ short Bs[2][64 * 64];
  const int m0 = blockIdx.x * 64;  // token tile
  const int h = blockIdx.y;        // head (N-tile of 64 = HD)
  const int tid = threadIdx.x;
  const int w = tid >> 6, lane = tid & 63, l15 = lane & 15, quad = lane >> 4;
  const short* wqh = WqT + (size_t)h * (HD * EMB);  // [d][e]
  f32x4 acc[4] = {};
  bf16x8 ar[2], br[2];
  load64(Xb, EMB, m0, 0, ar, tid);
  load64(wqh, EMB, 0, 0, br, tid);
  write64(As[0], ar, tid);
  write64(Bs[0], br, tid);
  load64(Xb, EMB, m0, 64, ar, tid);
  load64(wqh, EMB, 0, 64, br, tid);
  BAR();
  for (int k0 = 0; k0 < EMB; k0 += 64) {
    const int cur = (k0 >> 6) & 1;
    const short* Ac = As[cur];
    const short* Bc = Bs[cur];
    GEMM_TILE_COMPUTE(Ac, Bc, acc);
    if (k0 + 64 < EMB) {
      write64((short*)As[cur ^ 1], ar, tid);
      write64((short*)Bs[cur ^ 1], br, tid);
      if (k0 + 128 < EMB) {
        load64(Xb, EMB, m0, k0 + 128, ar, tid);
        load64(wqh, EMB, 0, k0 + 128, br, tid);
      }
    }
    BAR();
  }
  short* T = (short*)As[0];
#pragma unroll
  for (int nt = 0; nt < 4; ++nt)
#pragma unroll
    for (int r = 0; r < 4; ++r)
      T[SW64((w << 4) + (quad << 2) + r, (nt << 4) + l15)] = f2bf(acc[nt][r]);
  __syncthreads();
  {  // Qo[h][tok][d], coalesced b128 stores
    int r2 = tid >> 2, kb = (tid & 3) << 4;
    int g = kb >> 3;
    bf16x8 q0v = *(const bf16x8*)&T[r2 * 64 + ((g ^ (r2 & 7)) << 3)];
    bf16x8 q1v = *(const bf16x8*)&T[r2 * 64 + (((g + 1) ^ (r2 & 7)) << 3)];
    short* qo = Qo + (size_t)h * (BS_TOK * HD) + (size_t)(m0 + r2) * HD + kb;
    *(bf16x8*)(qo) = q0v;
    *(bf16x8*)(qo + 8) = q1v;
  }
  {  // Qt[h][d][tok], coalesced b128 stores
    int d = tid >> 2, tok0 = (tid & 3) << 4;
    bf16x8 t0, t1;
#pragma unroll
    for (int j = 0; j < 8; ++j) t0[j] = T[SW64(tok0 + j, d)];
#pragma unroll
    for (int j = 0; j < 8; ++j) t1[j] = T[SW64(tok0 + 8 + j, d)];
    short* qt = Qt + (size_t)h * (HD * BS_TOK) + (size_t)d * BS_TOK + m0 + tok0;
    *(bf16x8*)(qt) = t0;
    *(bf16x8*)(qt + 8) = t1;
  }
}

// ------------------------------------------------- flash attention, ksplit=1
// Paired K-tiles: quad-buffered K/V (4x8KB each), 2 P-regions per wave.
// Per iteration: publish next pair's staged regs, issue loads for pair+2,
// compute tile A then tile B (independent chains -> ILP), ONE barrier.
__device__ __forceinline__ void attn_tile(const short* __restrict__ K_,
                                          const short* __restrict__ V_,
                                          short* __restrict__ P_,
                                          const bf16x8 qf[2], f32x4 o[4],
                                          float& lpl, int l15, int quad) {
  f32x4 s[4];
  __builtin_amdgcn_s_setprio(1);
#pragma unroll
  for (int ct = 0; ct < 4; ++ct) {
    f32x4 a = (f32x4){0.f, 0.f, 0.f, 0.f};
#pragma unroll
    for (int ks = 0; ks < 2; ++ks) {
      int row = ct * 16 + l15;
      int c = ks * 4 + quad;
      bf16x8 kf = *(const bf16x8*)(&K_[row * 64 + ((c ^ (row & 7)) << 3)]);
      a = MFMA16(kf, qf[ks], a);
    }
    s[ct] = a;
  }
  __builtin_amdgcn_s_setprio(0);
  // no-max softmax: p = exp(s/8) = exp2(s*0.125*log2e); treed denominator adds
#pragma unroll
  for (int ct = 0; ct < 4; ++ct) {
    bf16x4 pv4;
    float pp[4];
#pragma unroll
    for (int r = 0; r < 4; ++r) {
      pp[r] = exp2f(s[ct][r] * 0.18033688011112042f);
      pv4[r] = f2bf(pp[r]);
    }
    lpl += (pp[0] + pp[1]) + (pp[2] + pp[3]);
    int g = 2 * ct + (quad >> 1);
    *(bf16x4*)&P_[l15 * 64 + ((g ^ (l15 & 7)) << 3) + ((quad & 1) << 2)] = pv4;
  }
  __builtin_amdgcn_s_setprio(1);
#pragma unroll
  for (int ks = 0; ks < 2; ++ks) {
    int c = ks * 4 + quad;
    bf16x8 pf = *(const bf16x8*)(&P_[l15 * 64 + ((c ^ (l15 & 7)) << 3)]);
#pragma unroll
    for (int dt = 0; dt < 4; ++dt) {
      int row = dt * 16 + l15;
      bf16x8 vf = *(const bf16x8*)(&V_[row * 64 + ((c ^ (row & 7)) << 3)]);
      o[dt] = MFMA16(pf, vf, o[dt]);
    }
  }
  __builtin_amdgcn_s_setprio(0);
}

__global__ __launch_bounds__(256) void attn_mfma_kernel(const short* __restrict__ Q,
                                                        const short* __restrict__ Qt,
                                                        short* __restrict__ Zcb) {
  __shared__ short Ks[4][64 * 64];     // 32 KB: K[key][d], quad-buffered
  __shared__ short Vt[4][64 * 64];     // 32 KB: V^T[d][key]
  __shared__ short Pw[4][2][16 * 64];  // 16 KB: per-wave, per-tile-in-pair
  const int h = blockIdx.y;
  const int q0 = blockIdx.x * 64;
  const int tid = threadIdx.x;
  const int lane = tid & 63;
  const int wv = tid >> 6;
  const int l15 = lane & 15;
  const int quad = lane >> 4;
  const short* Qh = Q + (size_t)h * (BS_TOK * HD);
  const short* Qth = Qt + (size_t)h * (HD * BS_TOK);
  short* myP0 = Pw[wv][0];
  short* myP1 = Pw[wv][1];

  bf16x8 qf[2];
  {
    const short* qp = Qh + (size_t)(q0 + wv * 16 + l15) * HD + quad * 8;
    qf[0] = *(const bf16x8*)(qp);
    qf[1] = *(const bf16x8*)(qp + 32);
  }

  f32x4 o[4] = {};
  float lpl = 0.f;  // denominator partial for qrow = l15

  bf16x8 kreg[2][2], vreg[2][2];
  // load pair 0 (tiles 0,1)
#pragma unroll
  for (int t = 0; t < 2; ++t)
#pragma unroll
    for (int i = 0; i < 2; ++i) {
      int c = i * 256 + tid;
      kreg[t][i] = *(const bf16x8*)(Qh + (size_t)t * 4096 + c * 8);
      vreg[t][i] = *(const bf16x8*)(Qth + (size_t)(c >> 3) * BS_TOK + t * 64 + (c & 7) * 8);
    }
  // publish pair 0 -> bufs 0,1
#pragma unroll
  for (int t = 0; t < 2; ++t)
#pragma unroll
    for (int i = 0; i < 2; ++i) {
      int c = i * 256 + tid, row = c >> 3, g = c & 7;
      *(bf16x8*)&Ks[t][row * 64 + ((g ^ (row & 7)) << 3)] = kreg[t][i];
      *(bf16x8*)&Vt[t][row * 64 + ((g ^ (row & 7)) << 3)] = vreg[t][i];
    }
  // load pair 1 (tiles 2,3) into regs
#pragma unroll
  for (int t = 0; t < 2; ++t)
#pragma unroll
    for (int i = 0; i < 2; ++i) {
      int c = i * 256 + tid;
      kreg[t][i] = *(const bf16x8*)(Qh + (size_t)(2 + t) * 4096 + c * 8);
      vreg[t][i] = *(const bf16x8*)(Qth + (size_t)(c >> 3) * BS_TOK + (2 + t) * 64 + (c & 7) * 8);
    }
  BAR();

  for (int p = 0; p < 16; ++p) {
    const int base = (p & 1) * 2;
    if (p + 1 < 16) {
      const int nb = ((p + 1) & 1) * 2;  // bufs last read in pair p-1 (BAR'd)
#pragma unroll
      for (int t = 0; t < 2; ++t)
#pragma unroll
        for (int i = 0; i < 2; ++i) {
          int c = i * 256 + tid, row = c >> 3, g = c & 7;
          *(bf16x8*)&Ks[nb + t][row * 64 + ((g ^ (row & 7)) << 3)] = kreg[t][i];
          *(bf16x8*)&Vt[nb + t][row * 64 + ((g ^ (row & 7)) << 3)] = vreg[t][i];
        }
      if (p + 2 < 16) {
        int gt0 = (p + 2) * 2;
#pragma unroll
        for (int t = 0; t < 2; ++t)
#pragma unroll
          for (int i = 0; i < 2; ++i) {
            int c = i * 256 + tid;
            kreg[t][i] = *(const bf16x8*)(Qh + (size_t)(gt0 + t) * 4096 + c * 8);
            vreg[t][i] = *(const bf16x8*)(Qth + (size_t)(c >> 3) * BS_TOK + (gt0 + t) * 64 + (c & 7) * 8);
          }
      }
    }
    attn_tile(Ks[base], Vt[base], myP0, qf, o, lpl, l15, quad);
    attn_tile(Ks[base + 1], Vt[base + 1], myP1, qf, o, lpl, l15, quad);
    BAR();
  }

  // full denominator per qrow=l15 (sum over quads), replicated across quads
  lpl += __shfl_xor(lpl, 16, 64);
  lpl += __shfl_xor(lpl, 32, 64);

  // per-output-row reciprocal: row quad*4+r's denom lives in lane l15=quad*4+r
  float rl[4];
#pragma unroll
  for (int r = 0; r < 4; ++r)
    rl[r] = 1.0f / __shfl(lpl, quad * 4 + r, 64);

  // stage bf16(o * 1/l) as [tok-local][d] tile, then ONE contiguous 8KB store
  short* T = (short*)Ks[0];  // safe: all waves past final BAR
#pragma unroll
  for (int dt = 0; dt < 4; ++dt)
#pragma unroll
    for (int r = 0; r < 4; ++r)
      T[SW64(wv * 16 + quad * 4 + r, dt * 16 + l15)] = f2bf(o[dt][r] * rl[r]);
  __syncthreads();
  {
    // Zc flat: z[h][n][d] at h*131072 + n*64 + d -> this tile is contiguous
    short* zo = Zcb + (size_t)h * (BS_TOK * HD) + (size_t)q0 * HD;
    int r2 = tid >> 2, kb = (tid & 3) << 4;
    int g = kb >> 3;
    bf16x8 z0 = *(const bf16x8*)&T[r2 * 64 + ((g ^ (r2 & 7)) << 3)];
    bf16x8 z1 = *(const bf16x8*)&T[r2 * 64 + (((g + 1) ^ (r2 & 7)) << 3)];
    *(bf16x8*)(zo + r2 * 64 + kb) = z0;
    *(bf16x8*)(zo + r2 * 64 + kb + 8) = z1;
  }
}

// ------------------------------------------------- MH = Wo * Zc (bf16), 128x64, ksplit=2
__global__ __launch_bounds__(256) void gemm_out_kernel(const short* __restrict__ Wob,
                                                       const short* __restrict__ Zcb,
                                                       float* __restrict__ Pp) {
  __shared__ short As[2][128 * 64];
  __shared__ short Bs[2][64 * 64];
  const int n0 = blockIdx.x * 64;   // j cols (2048 -> 32)
  const int m0 = blockIdx.y * 128;  // e rows (768 -> 6)
  const int kz = blockIdx.z * 384;  // K half
  const int tid = threadIdx.x;
  const int w = tid >> 6, lane = tid & 63, l15 = lane & 15, quad = lane >> 4;
  f32x4 acc[2][4] = {};
  bf16x8 ar[4], cr[2];
  load128(Wob, EMB, m0, kz, ar, tid);
  load_zc(Zcb, kz, n0, cr, tid);
  write128((short*)As[0], ar, tid);
  write_zc((short*)Bs[0], cr, tid);
  load128(Wob, EMB, m0, kz + 64, ar, tid);
  load_zc(Zcb, kz + 64, n0, cr, tid);
  BAR();
  for (int k0 = 0; k0 < 384; k0 += 64) {
    const int cur = (k0 >> 6) & 1;
    const short* Ac = As[cur];
    const short* Bc = Bs[cur];
    GEMM_TILE_COMPUTE2(Ac, Bc, acc);
    if (k0 + 64 < 384) {
      write128((short*)As[cur ^ 1], ar, tid);
      write_zc((short*)Bs[cur ^ 1], cr, tid);
      if (k0 + 128 < 384) {
        load128(Wob, EMB, m0, kz + k0 + 128, ar, tid);
        load_zc(Zcb, kz + k0 + 128, n0, cr, tid);
      }
    }
    BAR();
  }
  float* P = Pp + (size_t)blockIdx.z * (BS_TOK * EMB);
#pragma unroll
  for (int u = 0; u < 2; ++u)
#pragma unroll
    for (int nt = 0; nt < 4; ++nt)
#pragma unroll
      for (int r = 0; r < 4; ++r)
        P[(size_t)(m0 + (w << 5) + (u << 4) + (quad << 2) + r) * BS_TOK + n0 +
          (nt << 4) + l15] = acc[u][nt][r];
}

// ------------------------------------------------- FFN = L1b * fwb^T + fb, 128x64, ksplit=2
__global__ __launch_bounds__(256) void gemm_ffn_kernel(const short* __restrict__ L1b,
                                                       const short* __restrict__ Fwb,
                                                       const float* __restrict__ Fb,
                                                       float* __restrict__ Pp) {
  __shared__ short As[2][128 * 64];
  __shared__ short Bs[2][64 * 64];
  const int m0 = blockIdx.x * 128;  // token tile (16)
  const int n0 = blockIdx.y * 64;   // out-feature tile (12)
  const int kz = blockIdx.z * 384;  // K half
  const int tid = threadIdx.x;
  const int w = tid >> 6, lane = tid & 63, l15 = lane & 15, quad = lane >> 4;
  f32x4 acc[2][4] = {};
  bf16x8 ar[4], br[2];
  load128(L1b, EMB, m0, kz, ar, tid);
  load64(Fwb, EMB, n0, kz, br, tid);
  write128((short*)As[0], ar, tid);
  write64((short*)Bs[0], br, tid);
  load128(L1b, EMB, m0, kz + 64, ar, tid);
  load64(Fwb, EMB, n0, kz + 64, br, tid);
  BAR();
  for (int k0 = 0; k0 < 384; k0 += 64) {
    const int cur = (k0 >> 6) & 1;
    const short* Ac = As[cur];
    const short* Bc = Bs[cur];
    GEMM_TILE_COMPUTE2(Ac, Bc, acc);
    if (k0 + 64 < 384) {
      write128((short*)As[cur ^ 1], ar, tid);
      write64((short*)Bs[cur ^ 1], br, tid);
      if (k0 + 128 < 384) {
        load128(L1b, EMB, m0, kz + k0 + 128, ar, tid);
        load64(Fwb, EMB, n0, kz + k0 + 128, br, tid);
      }
    }
    BAR();
  }
  float* P = Pp + (size_t)blockIdx.z * (BS_TOK * EMB);
  const bool addb = (blockIdx.z == 0);
#pragma unroll
  for (int nt = 0; nt < 4; ++nt) {
    float bias = addb ? Fb[n0 + (nt << 4) + l15] : 0.0f;
#pragma unroll
    for (int u = 0; u < 2; ++u)
#pragma unroll
      for (int r = 0; r < 4; ++r)
        P[(size_t)(m0 + (w << 5) + (u << 4) + (quad << 2) + r) * EMB + n0 +
          (nt << 4) + l15] = acc[u][nt][r] + bias;
  }
}

// ------------------------------------------------- LN(Xa + P0 + P1) -> fp32 + bf16
// Wave-per-token: 4 tokens/block, shuffle-only reductions, no LDS/barriers.
__global__ __launch_bounds__(256) void ln_kernel(const float* __restrict__ Xa,
                                                 const float* __restrict__ P,
                                                 const float* __restrict__ g,
                                                 const float* __restrict__ bb,
                                                 float* __restrict__ Out,
                                                 short* __restrict__ Outb) {
  const int NB = BS_TOK * EMB;
  const int wv = threadIdx.x >> 6, lane = threadIdx.x & 63;
  const int t = blockIdx.x * 4 + wv;
  const float* xa = Xa + (size_t)t * EMB;
  const float* p0 = P + (size_t)t * EMB;
  const float* p1 = p0 + NB;
  float4 v[3];
  float s = 0.f;
#pragma unroll
  for (int i = 0; i < 3; ++i) {
    int e = lane * 4 + i * 256;
    float4 a = *(const float4*)(xa + e);
    float4 b = *(const float4*)(p0 + e);
    float4 c = *(const float4*)(p1 + e);
    v[i].x = a.x + b.x + c.x;
    v[i].y = a.y + b.y + c.y;
    v[i].z = a.z + b.z + c.z;
    v[i].w = a.w + b.w + c.w;
    s += v[i].x + v[i].y + v[i].z + v[i].w;
  }
#pragma unroll
  for (int o = 32; o > 0; o >>= 1) s += __shfl_xor(s, o, 64);
  float mu = s * (1.0f / EMB);
  float q = 0.f;
#pragma unroll
  for (int i = 0; i < 3; ++i) {
    float dx = v[i].x - mu, dy = v[i].y - mu, dz = v[i].z - mu, dw = v[i].w - mu;
    q += dx * dx + dy * dy + dz * dz + dw * dw;
  }
#pragma unroll
  for (int o = 32; o > 0; o >>= 1) q += __shfl_xor(q, o, 64);
  float var = q * (1.0f / EMB);
  float r = rsqrtf(var + 1e-5f);
#pragma unroll
  for (int i = 0; i < 3; ++i) {
    int e = lane * 4 + i * 256;
    float4 gg = *(const float4*)(g + e);
    float4 bv = *(const float4*)(bb + e);
    float4 res;
    res.x = (v[i].x - mu) * r * gg.x + bv.x;
    res.y = (v[i].y - mu) * r * gg.y + bv.y;
    res.z = (v[i].z - mu) * r * gg.z + bv.z;
    res.w = (v[i].w - mu) * r * gg.w + bv.w;
    *(float4*)(Out + (size_t)t * EMB + e) = res;
    bf16x4 ob;
    ob[0] = f2bf(res.x);
    ob[1] = f2bf(res.y);
    ob[2] = f2bf(res.z);
    ob[3] = f2bf(res.w);
    *(bf16x4*)(Outb + (size_t)t * EMB + e) = ob;
  }
}

extern "C" void kernel_launch(void* const* d_in, const int* in_sizes, int n_in,
                              void* d_out, int out_size, void* d_ws, size_t ws_size,
                              hipStream_t stream) {
  const float* tok = (const float*)d_in[0];
  const float* wq = (const float*)d_in[1];
  const float* wo = (const float*)d_in[2];
  const float* g1 = (const float*)d_in[3];
  const float* b1 = (const float*)d_in[4];
  const float* fw = (const float*)d_in[5];
  const float* fb = (const float*)d_in[6];
  const float* g2 = (const float*)d_in[7];
  const float* b2 = (const float*)d_in[8];
  const int NB = BS_TOK * EMB;  // 1572864 elems
  float* bufA = (float*)d_ws;        // X (residual, fp32)
  float* bufB = bufA + NB;           // gemm partial 0
  float* bufC = bufB + NB;           // gemm partial 1
  float* bufD = bufC + NB;           // L1 fp32
  short* XbA = (short*)(bufD + NB);  // bf16 of current X
  short* L1b = XbA + NB;             // bf16 of L1
  short* Qbf = L1b + NB;             // Q bf16 [H][2048][64]
  short* Qtb = Qbf + NB;             // Qt bf16 [H][64][2048]
  short* Zcb = Qtb + NB;             // attn out bf16, flat zc [768][2048]
  short* wqTb = Zcb + NB;            // wqT bf16 [L][H][64][768]
  short* wob = wqTb + WQN;           // wo bf16 [L][768][768]
  short* fwb = wob + WQN;            // fw bf16 [L][768][768]

  cvt_weights_kernel<<<dim3(WQN / (256 * 8), 2), 256, 0, stream>>>(wo, fw, wob, fwb);
  wq_trans_kernel<<<dim3(12, 12 * NH), 256, 0, stream>>>(wq, wqTb);
  pe_add_kernel<<<NB / 256, 256, 0, stream>>>(tok, bufA, XbA);
  for (int it = 0; it < 13; ++it) {
    int l = (it == 0) ? 0 : it - 1;  // layer 0 applied twice (faithful)
    gemm_q_kernel<<<dim3(32, NH), 256, 0, stream>>>(
        XbA, wqTb + (size_t)l * (NH * HD * EMB), Qbf, Qtb);
    attn_mfma_kernel<<<dim3(32, NH), 256, 0, stream>>>(Qbf, Qtb, Zcb);
    gemm_out_kernel<<<dim3(32, 6, 2), 256, 0, stream>>>(
        wob + (size_t)l * (EMB * EMB), Zcb, bufB);
    ln_kernel<<<BS_TOK / 4, 256, 0, stream>>>(bufA, bufB, g1 + l * EMB, b1 + l * EMB,
                                              bufD, L1b);
    gemm_ffn_kernel<<<dim3(16, 12, 2), 256, 0, stream>>>(
        L1b, fwb + (size_t)l * (EMB * EMB), fb + l * EMB, bufB);
    float* ln2_dst = (it == 12) ? (float*)d_out : bufA;
    ln_kernel<<<BS_TOK / 4, 256, 0, stream>>>(bufD, bufB, g2 + l * EMB, b2 + l * EMB,
                                              ln2_dst, XbA);
  }
}

// Round 12
// 1111.485 us; speedup vs baseline: 6.2475x; 1.0607x over previous
//
#include <hip/hip_runtime.h>
#include <hip/hip_bf16.h>

// BERT stack: L=12(+1 dup of layer0), H=12, E=768, D=64, B=4, S=512 -> BS=2048 tokens.
// Faithful bugs preserved:
//  - attention flattens batch: 2048 tokens attend to each other globally, q==k==v
//  - zc = z.reshape(768,2048) is a FLAT VIEW of z[H][N][D]  (no transpose)
//  - mh = (wo@zc).reshape(B,S,E) is a FLAT VIEW of mh_mat[768][2048]
//  - pe: p = 10000 for e<384 else 10001; even e -> sin, odd -> cos; s = t % 512
// History: R1-R3 inner-loop opts NEUTRAL; R4-R6 persistent kernel refuted.
// R7/R8 profile: attn 44->42.8us at MfmaUtil 11%, Occupancy 12% (= 1 wave/SIMD;
// grid 384 blocks = 1.5/CU, 128 CUs run 2 blocks serially). ILP pairing
// neutral -> wave starvation + block imbalance is the limiter.
// R9 (4th submission after three infra timeouts): attention re-decomposed for
// OCCUPANCY: Q-tile 32, 4 waves = 2 q-subwaves x 2 key-halves; grid 64x12=768
// = exactly 3 blocks/CU BALANCED, 3 waves/SIMD. LDS 40KB (single-buffered K/V
// per half, overlaid combine scratch) so 3 blocks co-reside;
// launch_bounds(256,3). Key-half fp32 partials combined in-block via LDS,
// output path unchanged (contiguous bf16 Zc tile).

#define BS_TOK 2048
#define EMB 768
#define NH 12
#define HD 64
#define WQN (12 * NH * EMB * HD)  // elems per weight stack (7077888)

typedef __attribute__((ext_vector_type(8))) short bf16x8;
typedef __attribute__((ext_vector_type(4))) short bf16x4;
typedef __attribute__((ext_vector_type(4))) float f32x4;

__device__ __forceinline__ short f2bf(float f) {
  union { __hip_bfloat16 h; short s; } u;
  u.h = __float2bfloat16(f);
  return u.s;
}

#define MFMA16(a, b, c) __builtin_amdgcn_mfma_f32_16x16x32_bf16(a, b, c, 0, 0, 0)
// XOR-swizzled LDS address for [r][k] tiles, 64-elem rows (zero-conflict)
#define SW64(r, k) ((r) * 64 + ((((k) >> 3) ^ ((r) & 7)) << 3) + ((k) & 7))
// Barrier that drains LDS ops only — in-flight global loads cross it.
#define BAR() asm volatile("s_waitcnt lgkmcnt(0)\n\ts_barrier" ::: "memory")

// ---------------------------------------------------------------- weight prep
__global__ __launch_bounds__(256) void cvt_weights_kernel(const float* __restrict__ wo,
                                                          const float* __restrict__ fw,
                                                          short* __restrict__ wob,
                                                          short* __restrict__ fwb) {
  const float* src = blockIdx.y ? fw : wo;
  short* dst = blockIdx.y ? fwb : wob;
  int i = (blockIdx.x * 256 + threadIdx.x) * 8;
  float4 a = *(const float4*)(src + i);
  float4 b = *(const float4*)(src + i + 4);
  bf16x8 t;
  t[0] = f2bf(a.x); t[1] = f2bf(a.y); t[2] = f2bf(a.z); t[3] = f2bf(a.w);
  t[4] = f2bf(b.x); t[5] = f2bf(b.y); t[6] = f2bf(b.z); t[7] = f2bf(b.w);
  *(bf16x8*)(dst + i) = t;
}

// wqT[l][h][d][e] <- wq[l][h][e][d], bf16
__global__ __launch_bounds__(256) void wq_trans_kernel(const float* __restrict__ wq,
                                                       short* __restrict__ wqT) {
  __shared__ short T[64 * 64];
  const int et = blockIdx.x;  // e-tile (12)
  const int lh = blockIdx.y;  // l*NH+h (144)
  const int tid = threadIdx.x;
  const float* src = wq + ((size_t)lh * EMB + et * 64) * HD;
  {
    int r = tid >> 2, c16 = (tid & 3) << 4;
    const float* p = src + r * HD + c16;
    float4 x0 = *(const float4*)(p + 0);
    float4 x1 = *(const float4*)(p + 4);
    float4 x2 = *(const float4*)(p + 8);
    float4 x3 = *(const float4*)(p + 12);
    bf16x8 a, b;
    a[0] = f2bf(x0.x); a[1] = f2bf(x0.y); a[2] = f2bf(x0.z); a[3] = f2bf(x0.w);
    a[4] = f2bf(x1.x); a[5] = f2bf(x1.y); a[6] = f2bf(x1.z); a[7] = f2bf(x1.w);
    b[0] = f2bf(x2.x); b[1] = f2bf(x2.y); b[2] = f2bf(x2.z); b[3] = f2bf(x2.w);
    b[4] = f2bf(x3.x); b[5] = f2bf(x3.y); b[6] = f2bf(x3.z); b[7] = f2bf(x3.w);
    int g = c16 >> 3;
    *(bf16x8*)&T[r * 64 + ((g ^ (r & 7)) << 3)] = a;
    *(bf16x8*)&T[r * 64 + (((g + 1) ^ (r & 7)) << 3)] = b;
  }
  __syncthreads();
  {
    int d = tid >> 2, e16 = (tid & 3) << 4;
    bf16x8 t0, t1;
#pragma unroll
    for (int j = 0; j < 8; ++j) t0[j] = T[SW64(e16 + j, d)];
#pragma unroll
    for (int j = 0; j < 8; ++j) t1[j] = T[SW64(e16 + 8 + j, d)];
    short* q = wqT + ((size_t)lh * HD + d) * EMB + et * 64 + e16;
    *(bf16x8*)(q) = t0;
    *(bf16x8*)(q + 8) = t1;
  }
}

// ---------------------------------------------------------------- pe + tokens
__global__ __launch_bounds__(256) void pe_add_kernel(const float* __restrict__ tok,
                                                     float* __restrict__ X,
                                                     short* __restrict__ Xb) {
  int idx = blockIdx.x * 256 + threadIdx.x;   // < 2048*768
  int e = idx % EMB;
  int t = idx / EMB;
  int s = t & 511;                            // t = b*512 + s
  float p = (e < 384) ? 10000.0f : 10001.0f;  // 10000 XOR ((2e)//768)
  float ang = (float)s / p;
  float pe = (e & 1) ? cosf(ang) : sinf(ang);
  float v = tok[idx] + pe;
  X[idx] = v;
  Xb[idx] = f2bf(v);
}

// ---------------- staging helpers (split load/write for reg-prefetch pipeline)
__device__ __forceinline__ void load64(const short* __restrict__ src, int ld,
                                       int row0, int k0, bf16x8* r, int tid) {
  int rr = tid >> 2, kb = (tid & 3) << 4;
  const short* p = src + (size_t)(row0 + rr) * ld + k0 + kb;
  r[0] = *(const bf16x8*)(p);
  r[1] = *(const bf16x8*)(p + 8);
}
__device__ __forceinline__ void write64(short* dst, const bf16x8* r, int tid) {
  int rr = tid >> 2, g = (tid & 3) << 1;
  *(bf16x8*)&dst[rr * 64 + (((g + 0) ^ (rr & 7)) << 3)] = r[0];
  *(bf16x8*)&dst[rr * 64 + (((g + 1) ^ (rr & 7)) << 3)] = r[1];
}

__device__ __forceinline__ void load128(const short* __restrict__ src, int ld,
                                        int row0, int k0, bf16x8* r, int tid) {
  int rr = tid >> 1, kb = (tid & 1) << 5;
  const short* p = src + (size_t)(row0 + rr) * ld + k0 + kb;
  r[0] = *(const bf16x8*)(p);
  r[1] = *(const bf16x8*)(p + 8);
  r[2] = *(const bf16x8*)(p + 16);
  r[3] = *(const bf16x8*)(p + 24);
}
__device__ __forceinline__ void write128(short* dst, const bf16x8* r, int tid) {
  int rr = tid >> 1, g = (tid & 1) << 2;
#pragma unroll
  for (int i = 0; i < 4; ++i)
    *(bf16x8*)&dst[rr * 64 + (((g + i) ^ (rr & 7)) << 3)] = r[i];
}

// B-staging for gemm_out from bf16 Zcb (flat [768][2048] row-major):
// dst[n][k] <- Zcb[(k0+k)*2048 + col0+n]  (transpose via swizzled LDS scatter)
__device__ __forceinline__ void load_zc(const short* __restrict__ Zcb,
                                        int k0, int col0, bf16x8 cr[2], int tid) {
  int kk = tid >> 2, nb = (tid & 3) << 4;
  const short* p = Zcb + (size_t)(k0 + kk) * BS_TOK + col0 + nb;
  cr[0] = *(const bf16x8*)(p);
  cr[1] = *(const bf16x8*)(p + 8);
}
__device__ __forceinline__ void write_zc(short* dst, const bf16x8 cr[2], int tid) {
  int kk = tid >> 2, nb = (tid & 3) << 4;
#pragma unroll
  for (int j = 0; j < 8; ++j) dst[SW64(nb + j, kk)] = cr[0][j];
#pragma unroll
  for (int j = 0; j < 8; ++j) dst[SW64(nb + 8 + j, kk)] = cr[1][j];
}

#define GEMM_TILE_COMPUTE(As, Bs, acc)                                              \
  {                                                                                 \
    _Pragma("unroll") for (int s = 0; s < 2; ++s) {                                 \
      int ra = (w << 4) + l15;                                                      \
      bf16x8 af = *(const bf16x8*)&As[ra * 64 + ((((s << 2) + quad) ^ (ra & 7)) << 3)]; \
      _Pragma("unroll") for (int nt = 0; nt < 4; ++nt) {                            \
        int rb = (nt << 4) + l15;                                                   \
        bf16x8 bf = *(const bf16x8*)&Bs[rb * 64 + ((((s << 2) + quad) ^ (rb & 7)) << 3)]; \
        acc[nt] = MFMA16(af, bf, acc[nt]);                                          \
      }                                                                             \
    }                                                                               \
  }

#define GEMM_TILE_COMPUTE2(As, Bs, acc)                                             \
  {                                                                                 \
    _Pragma("unroll") for (int s = 0; s < 2; ++s) {                                 \
      bf16x8 af[2];                                                                 \
      _Pragma("unroll") for (int u = 0; u < 2; ++u) {                               \
        int ra = (w << 5) + (u << 4) + l15;                                         \
        af[u] = *(const bf16x8*)&As[ra * 64 + ((((s << 2) + quad) ^ (ra & 7)) << 3)]; \
      }                                                                             \
      _Pragma("unroll") for (int nt = 0; nt < 4; ++nt) {                            \
        int rb = (nt << 4) + l15;                                                   \
        bf16x8 bf = *(const bf16x8*)&Bs[rb * 64 + ((((s << 2) + quad) ^ (rb & 7)) << 3)]; \
        acc[0][nt] = MFMA16(af[0], bf, acc[0][nt]);                                 \
        acc[1][nt] = MFMA16(af[1], bf, acc[1][nt]);                                 \
      }                                                                             \
    }                                                                               \
  }

// ------------------------------------------------- Q = Xb[2048x768] * WqT -> bf16 Q + Qt
__global__ __launch_bounds__(256) void gemm_q_kernel(const short* __restrict__ Xb,
                                                     const short* __restrict__ WqT,
                                                     short* __restrict__ Qo,
                                                     short* __restrict__ Qt) {
  __shared__ short As[2][64 * 64];
  __shared__ short Bs[2][64 * 64];
  const int m0 = blockIdx.x * 64;  // token tile
  const int h = blockIdx.y;        // head (N-tile of 64 = HD)
  const int tid = threadIdx.x;
  const int w = tid >> 6, lane = tid & 63, l15 = lane & 15, quad = lane >> 4;
  const short* wqh = WqT + (size_t)h * (HD * EMB);  // [d][e]
  f32x4 acc[4] = {};
  bf16x8 ar[2], br[2];
  load64(Xb, EMB, m0, 0, ar, tid);
  load64(wqh, EMB, 0, 0, br, tid);
  write64(As[0], ar, tid);
  write64(Bs[0], br, tid);
  load64(Xb, EMB, m0, 64, ar, tid);
  load64(wqh, EMB, 0, 64, br, tid);
  BAR();
  for (int k0 = 0; k0 < EMB; k0 += 64) {
    const int cur = (k0 >> 6) & 1;
    const short* Ac = As[cur];
    const short* Bc = Bs[cur];
    GEMM_TILE_COMPUTE(Ac, Bc, acc);
    if (k0 + 64 < EMB) {
      write64((short*)As[cur ^ 1], ar, tid);
      write64((short*)Bs[cur ^ 1], br, tid);
      if (k0 + 128 < EMB) {
        load64(Xb, EMB, m0, k0 + 128, ar, tid);
        load64(wqh, EMB, 0, k0 + 128, br, tid);
      }
    }
    BAR();
  }
  short* T = (short*)As[0];
#pragma unroll
  for (int nt = 0; nt < 4; ++nt)
#pragma unroll
    for (int r = 0; r < 4; ++r)
      T[SW64((w << 4) + (quad << 2) + r, (nt << 4) + l15)] = f2bf(acc[nt][r]);
  __syncthreads();
  {  // Qo[h][tok][d], coalesced b128 stores
    int r2 = tid >> 2, kb = (tid & 3) << 4;
    int g = kb >> 3;
    bf16x8 q0v = *(const bf16x8*)&T[r2 * 64 + ((g ^ (r2 & 7)) << 3)];
    bf16x8 q1v = *(const bf16x8*)&T[r2 * 64 + (((g + 1) ^ (r2 & 7)) << 3)];
    short* qo = Qo + (size_t)h * (BS_TOK * HD) + (size_t)(m0 + r2) * HD + kb;
    *(bf16x8*)(qo) = q0v;
    *(bf16x8*)(qo + 8) = q1v;
  }
  {  // Qt[h][d][tok], coalesced b128 stores
    int d = tid >> 2, tok0 = (tid & 3) << 4;
    bf16x8 t0, t1;
#pragma unroll
    for (int j = 0; j < 8; ++j) t0[j] = T[SW64(tok0 + j, d)];
#pragma unroll
    for (int j = 0; j < 8; ++j) t1[j] = T[SW64(tok0 + 8 + j, d)];
    short* qt = Qt + (size_t)h * (HD * BS_TOK) + (size_t)d * BS_TOK + m0 + tok0;
    *(bf16x8*)(qt) = t0;
    *(bf16x8*)(qt + 8) = t1;
  }
}

// ------------------------------------------------- flash attention
// R9: Q-tile 32, 4 waves = 2 q-subwaves x 2 key-halves; grid 64x12 = 768
// blocks = 3/CU balanced, 3 waves/SIMD. Single-buffered K/V per half (40KB
// LDS total incl. P + overlaid combine scratch). Key-half fp32 partials
// combined in-block; final bf16 Z/l written to flat-zc (contiguous 4KB tile).
__device__ __forceinline__ void attn_tile(const short* __restrict__ K_,
                                          const short* __restrict__ V_,
                                          short* __restrict__ P_,
                                          const bf16x8 qf[2], f32x4 o[4],
                                          float& lpl, int l15, int quad) {
  f32x4 s[4];
  __builtin_amdgcn_s_setprio(1);
#pragma unroll
  for (int ct = 0; ct < 4; ++ct) {
    f32x4 a = (f32x4){0.f, 0.f, 0.f, 0.f};
#pragma unroll
    for (int ks = 0; ks < 2; ++ks) {
      int row = ct * 16 + l15;
      int c = ks * 4 + quad;
      bf16x8 kf = *(const bf16x8*)(&K_[row * 64 + ((c ^ (row & 7)) << 3)]);
      a = MFMA16(kf, qf[ks], a);
    }
    s[ct] = a;
  }
  __builtin_amdgcn_s_setprio(0);
  // no-max softmax: p = exp(s/8) = exp2(s*0.125*log2e)
#pragma unroll
  for (int ct = 0; ct < 4; ++ct) {
    bf16x4 pv4;
    float pp[4];
#pragma unroll
    for (int r = 0; r < 4; ++r) {
      pp[r] = exp2f(s[ct][r] * 0.18033688011112042f);
      pv4[r] = f2bf(pp[r]);
    }
    lpl += (pp[0] + pp[1]) + (pp[2] + pp[3]);
    int g = 2 * ct + (quad >> 1);
    *(bf16x4*)&P_[l15 * 64 + ((g ^ (l15 & 7)) << 3) + ((quad & 1) << 2)] = pv4;
  }
  __builtin_amdgcn_s_setprio(1);
#pragma unroll
  for (int ks = 0; ks < 2; ++ks) {
    int c = ks * 4 + quad;
    bf16x8 pf = *(const bf16x8*)(&P_[l15 * 64 + ((c ^ (l15 & 7)) << 3)]);
#pragma unroll
    for (int dt = 0; dt < 4; ++dt) {
      int row = dt * 16 + l15;
      bf16x8 vf = *(const bf16x8*)(&V_[row * 64 + ((c ^ (row & 7)) << 3)]);
      o[dt] = MFMA16(pf, vf, o[dt]);
    }
  }
  __builtin_amdgcn_s_setprio(0);
}

__global__ __launch_bounds__(256, 3) void attn_mfma_kernel(const short* __restrict__ Q,
                                                           const short* __restrict__ Qt,
                                                           short* __restrict__ Zcb) {
  __shared__ short sm[20480];  // 40 KB
  // layout (shorts): Ks[half] at hb*4096; Vt[half] at 8192+hb*4096;
  // Pw[wv] at 16384+wv*1024. Overlays after final loop BAR (regions dead):
  // Fo fp32[32][64] at short-offset 0, Fl fp32[32] at float-offset 2048,
  // T bf16[32][64] at short-offset 8192.
  const int h = blockIdx.y;
  const int q0 = blockIdx.x * 32;
  const int tid = threadIdx.x;
  const int lane = tid & 63;
  const int wv = tid >> 6;
  const int wq = wv & 1;   // q-subwave (16 rows)
  const int hb = wv >> 1;  // key half (0: keys 0-1023, 1: 1024-2047)
  const int l15 = lane & 15;
  const int quad = lane >> 4;
  const short* Qh = Q + (size_t)h * (BS_TOK * HD);
  const short* Qth = Qt + (size_t)h * (HD * BS_TOK);
  short* Ksh = sm + hb * 4096;
  short* Vth = sm + 8192 + hb * 4096;
  short* myP = sm + 16384 + wv * 1024;

  bf16x8 qf[2];
  {
    const short* qp = Qh + (size_t)(q0 + wq * 16 + l15) * HD + quad * 8;
    qf[0] = *(const bf16x8*)(qp);
    qf[1] = *(const bf16x8*)(qp + 32);
  }

  f32x4 o[4] = {};
  float lpl = 0.f;  // denominator partial for qrow = l15 (this key half)

  // staging: each half's 128 threads stage that half's tiles (4+4 b128/thread)
  const int t128 = tid & 127;
  bf16x8 kreg[4], vreg[4];
#pragma unroll
  for (int i = 0; i < 4; ++i) {  // tile hb*16
    int c = i * 128 + t128;
    kreg[i] = *(const bf16x8*)(Qh + (size_t)(hb * 16) * 4096 + c * 8);
    vreg[i] = *(const bf16x8*)(Qth + (size_t)(c >> 3) * BS_TOK + (hb * 16) * 64 + (c & 7) * 8);
  }
#pragma unroll
  for (int i = 0; i < 4; ++i) {
    int c = i * 128 + t128, row = c >> 3, g = c & 7;
    *(bf16x8*)&Ksh[row * 64 + ((g ^ (row & 7)) << 3)] = kreg[i];
    *(bf16x8*)&Vth[row * 64 + ((g ^ (row & 7)) << 3)] = vreg[i];
  }
#pragma unroll
  for (int i = 0; i < 4; ++i) {  // tile hb*16+1 in flight
    int c = i * 128 + t128;
    kreg[i] = *(const bf16x8*)(Qh + (size_t)(hb * 16 + 1) * 4096 + c * 8);
    vreg[i] = *(const bf16x8*)(Qth + (size_t)(c >> 3) * BS_TOK + (hb * 16 + 1) * 64 + (c & 7) * 8);
  }
  BAR();

  for (int t = 0; t < 16; ++t) {
    attn_tile(Ksh, Vth, myP, qf, o, lpl, l15, quad);
    BAR();  // all reads of the single buffer done
    if (t + 1 < 16) {
#pragma unroll
      for (int i = 0; i < 4; ++i) {
        int c = i * 128 + t128, row = c >> 3, g = c & 7;
        *(bf16x8*)&Ksh[row * 64 + ((g ^ (row & 7)) << 3)] = kreg[i];
        *(bf16x8*)&Vth[row * 64 + ((g ^ (row & 7)) << 3)] = vreg[i];
      }
      if (t + 2 < 16) {
        int gt = hb * 16 + t + 2;
#pragma unroll
        for (int i = 0; i < 4; ++i) {
          int c = i * 128 + t128;
          kreg[i] = *(const bf16x8*)(Qh + (size_t)gt * 4096 + c * 8);
          vreg[i] = *(const bf16x8*)(Qth + (size_t)(c >> 3) * BS_TOK + gt * 64 + (c & 7) * 8);
        }
      }
    }
    BAR();  // writes visible for next compute
  }

  // full denominator for this half per qrow=l15 (sum over quads)
  lpl += __shfl_xor(lpl, 16, 64);
  lpl += __shfl_xor(lpl, 32, 64);

  // combine key halves via LDS (overlays Ks region — dead after final BAR)
  float* Fo = (float*)sm;           // [2 wq][16 row][64 d] = 8KB
  float* Fl = (float*)sm + 2048;    // [2 wq][16]
  if (hb == 1) {
#pragma unroll
    for (int dt = 0; dt < 4; ++dt)
#pragma unroll
      for (int r = 0; r < 4; ++r)
        Fo[(wq * 16 + quad * 4 + r) * 64 + dt * 16 + l15] = o[dt][r];
    if (quad == 0) Fl[wq * 16 + l15] = lpl;
  }
  __syncthreads();
  short* T = sm + 8192;  // [32 tok][64 d] swizzled, overlays Vt[0]
  if (hb == 0) {
#pragma unroll
    for (int dt = 0; dt < 4; ++dt)
#pragma unroll
      for (int r = 0; r < 4; ++r)
        o[dt][r] += Fo[(wq * 16 + quad * 4 + r) * 64 + dt * 16 + l15];
    float ltot = lpl + Fl[wq * 16 + l15];
    float rl[4];
#pragma unroll
    for (int r = 0; r < 4; ++r)
      rl[r] = 1.0f / __shfl(ltot, quad * 4 + r, 64);
#pragma unroll
    for (int dt = 0; dt < 4; ++dt)
#pragma unroll
      for (int r = 0; r < 4; ++r)
        T[SW64(wq * 16 + quad * 4 + r, dt * 16 + l15)] = f2bf(o[dt][r] * rl[r]);
  }
  __syncthreads();
  {
    // Zc flat: z[h][n][d] at h*131072 + n*64 + d -> this 32x64 tile contiguous
    short* zo = Zcb + (size_t)h * (BS_TOK * HD) + (size_t)q0 * HD;
    int r2 = tid >> 3, g = tid & 7;  // 32 rows x 8 b128-chunks
    bf16x8 z = *(const bf16x8*)&T[r2 * 64 + ((g ^ (r2 & 7)) << 3)];
    *(bf16x8*)(zo + r2 * 64 + g * 8) = z;
  }
}

// ------------------------------------------------- MH = Wo * Zc (bf16), 128x64, ksplit=2
__global__ __launch_bounds__(256) void gemm_out_kernel(const short* __restrict__ Wob,
                                                       const short* __restrict__ Zcb,
                                                       float* __restrict__ Pp) {
  __shared__ short As[2][128 * 64];
  __shared__ short Bs[2][64 * 64];
  const int n0 = blockIdx.x * 64;   // j cols (2048 -> 32)
  const int m0 = blockIdx.y * 128;  // e rows (768 -> 6)
  const int kz = blockIdx.z * 384;  // K half
  const int tid = threadIdx.x;
  const int w = tid >> 6, lane = tid & 63, l15 = lane & 15, quad = lane >> 4;
  f32x4 acc[2][4] = {};
  bf16x8 ar[4], cr[2];
  load128(Wob, EMB, m0, kz, ar, tid);
  load_zc(Zcb, kz, n0, cr, tid);
  write128((short*)As[0], ar, tid);
  write_zc((short*)Bs[0], cr, tid);
  load128(Wob, EMB, m0, kz + 64, ar, tid);
  load_zc(Zcb, kz + 64, n0, cr, tid);
  BAR();
  for (int k0 = 0; k0 < 384; k0 += 64) {
    const int cur = (k0 >> 6) & 1;
    const short* Ac = As[cur];
    const short* Bc = Bs[cur];
    GEMM_TILE_COMPUTE2(Ac, Bc, acc);
    if (k0 + 64 < 384) {
      write128((short*)As[cur ^ 1], ar, tid);
      write_zc((short*)Bs[cur ^ 1], cr, tid);
      if (k0 + 128 < 384) {
        load128(Wob, EMB, m0, kz + k0 + 128, ar, tid);
        load_zc(Zcb, kz + k0 + 128, n0, cr, tid);
      }
    }
    BAR();
  }
  float* P = Pp + (size_t)blockIdx.z * (BS_TOK * EMB);
#pragma unroll
  for (int u = 0; u < 2; ++u)
#pragma unroll
    for (int nt = 0; nt < 4; ++nt)
#pragma unroll
      for (int r = 0; r < 4; ++r)
        P[(size_t)(m0 + (w << 5) + (u << 4) + (quad << 2) + r) * BS_TOK + n0 +
          (nt << 4) + l15] = acc[u][nt][r];
}

// ------------------------------------------------- FFN = L1b * fwb^T + fb, 128x64, ksplit=2
__global__ __launch_bounds__(256) void gemm_ffn_kernel(const short* __restrict__ L1b,
                                                       const short* __restrict__ Fwb,
                                                       const float* __restrict__ Fb,
                                                       float* __restrict__ Pp) {
  __shared__ short As[2][128 * 64];
  __shared__ short Bs[2][64 * 64];
  const int m0 = blockIdx.x * 128;  // token tile (16)
  const int n0 = blockIdx.y * 64;   // out-feature tile (12)
  const int kz = blockIdx.z * 384;  // K half
  const int tid = threadIdx.x;
  const int w = tid >> 6, lane = tid & 63, l15 = lane & 15, quad = lane >> 4;
  f32x4 acc[2][4] = {};
  bf16x8 ar[4], br[2];
  load128(L1b, EMB, m0, kz, ar, tid);
  load64(Fwb, EMB, n0, kz, br, tid);
  write128((short*)As[0], ar, tid);
  write64((short*)Bs[0], br, tid);
  load128(L1b, EMB, m0, kz + 64, ar, tid);
  load64(Fwb, EMB, n0, kz + 64, br, tid);
  BAR();
  for (int k0 = 0; k0 < 384; k0 += 64) {
    const int cur = (k0 >> 6) & 1;
    const short* Ac = As[cur];
    const short* Bc = Bs[cur];
    GEMM_TILE_COMPUTE2(Ac, Bc, acc);
    if (k0 + 64 < 384) {
      write128((short*)As[cur ^ 1], ar, tid);
      write64((short*)Bs[cur ^ 1], br, tid);
      if (k0 + 128 < 384) {
        load128(L1b, EMB, m0, kz + k0 + 128, ar, tid);
        load64(Fwb, EMB, n0, kz + k0 + 128, br, tid);
      }
    }
    BAR();
  }
  float* P = Pp + (size_t)blockIdx.z * (BS_TOK * EMB);
  const bool addb = (blockIdx.z == 0);
#pragma unroll
  for (int nt = 0; nt < 4; ++nt) {
    float bias = addb ? Fb[n0 + (nt << 4) + l15] : 0.0f;
#pragma unroll
    for (int u = 0; u < 2; ++u)
#pragma unroll
      for (int r = 0; r < 4; ++r)
        P[(size_t)(m0 + (w << 5) + (u << 4) + (quad << 2) + r) * EMB + n0 +
          (nt << 4) + l15] = acc[u][nt][r] + bias;
  }
}

// ------------------------------------------------- LN(Xa + P0 + P1) -> fp32 + bf16
// Wave-per-token: 4 tokens/block, shuffle-only reductions, no LDS/barriers.
__global__ __launch_bounds__(256) void ln_kernel(const float* __restrict__ Xa,
                                                 const float* __restrict__ P,
                                                 const float* __restrict__ g,
                                                 const float* __restrict__ bb,
                                                 float* __restrict__ Out,
                                                 short* __restrict__ Outb) {
  const int NB = BS_TOK * EMB;
  const int wv = threadIdx.x >> 6, lane = threadIdx.x & 63;
  const int t = blockIdx.x * 4 + wv;
  const float* xa = Xa + (size_t)t * EMB;
  const float* p0 = P + (size_t)t * EMB;
  const float* p1 = p0 + NB;
  float4 v[3];
  float s = 0.f;
#pragma unroll
  for (int i = 0; i < 3; ++i) {
    int e = lane * 4 + i * 256;
    float4 a = *(const float4*)(xa + e);
    float4 b = *(const float4*)(p0 + e);
    float4 c = *(const float4*)(p1 + e);
    v[i].x = a.x + b.x + c.x;
    v[i].y = a.y + b.y + c.y;
    v[i].z = a.z + b.z + c.z;
    v[i].w = a.w + b.w + c.w;
    s += v[i].x + v[i].y + v[i].z + v[i].w;
  }
#pragma unroll
  for (int o = 32; o > 0; o >>= 1) s += __shfl_xor(s, o, 64);
  float mu = s * (1.0f / EMB);
  float q = 0.f;
#pragma unroll
  for (int i = 0; i < 3; ++i) {
    float dx = v[i].x - mu, dy = v[i].y - mu, dz = v[i].z - mu, dw = v[i].w - mu;
    q += dx * dx + dy * dy + dz * dz + dw * dw;
  }
#pragma unroll
  for (int o = 32; o > 0; o >>= 1) q += __shfl_xor(q, o, 64);
  float var = q * (1.0f / EMB);
  float r = rsqrtf(var + 1e-5f);
#pragma unroll
  for (int i = 0; i < 3; ++i) {
    int e = lane * 4 + i * 256;
    float4 gg = *(const float4*)(g + e);
    float4 bv = *(const float4*)(bb + e);
    float4 res;
    res.x = (v[i].x - mu) * r * gg.x + bv.x;
    res.y = (v[i].y - mu) * r * gg.y + bv.y;
    res.z = (v[i].z - mu) * r * gg.z + bv.z;
    res.w = (v[i].w - mu) * r * gg.w + bv.w;
    *(float4*)(Out + (size_t)t * EMB + e) = res;
    bf16x4 ob;
    ob[0] = f2bf(res.x);
    ob[1] = f2bf(res.y);
    ob[2] = f2bf(res.z);
    ob[3] = f2bf(res.w);
    *(bf16x4*)(Outb + (size_t)t * EMB + e) = ob;
  }
}

extern "C" void kernel_launch(void* const* d_in, const int* in_sizes, int n_in,
                              void* d_out, int out_size, void* d_ws, size_t ws_size,
                              hipStream_t stream) {
  const float* tok = (const float*)d_in[0];
  const float* wq = (const float*)d_in[1];
  const float* wo = (const float*)d_in[2];
  const float* g1 = (const float*)d_in[3];
  const float* b1 = (const float*)d_in[4];
  const float* fw = (const float*)d_in[5];
  const float* fb = (const float*)d_in[6];
  const float* g2 = (const float*)d_in[7];
  const float* b2 = (const float*)d_in[8];
  const int NB = BS_TOK * EMB;  // 1572864 elems
  float* bufA = (float*)d_ws;        // X (residual, fp32)
  float* bufB = bufA + NB;           // gemm partial 0
  float* bufC = bufB + NB;           // gemm partial 1
  float* bufD = bufC + NB;           // L1 fp32
  short* XbA = (short*)(bufD + NB);  // bf16 of current X
  short* L1b = XbA + NB;             // bf16 of L1
  short* Qbf = L1b + NB;             // Q bf16 [H][2048][64]
  short* Qtb = Qbf + NB;             // Qt bf16 [H][64][2048]
  short* Zcb = Qtb + NB;             // attn out bf16, flat zc [768][2048]
  short* wqTb = Zcb + NB;            // wqT bf16 [L][H][64][768]
  short* wob = wqTb + WQN;           // wo bf16 [L][768][768]
  short* fwb = wob + WQN;            // fw bf16 [L][768][768]

  cvt_weights_kernel<<<dim3(WQN / (256 * 8), 2), 256, 0, stream>>>(wo, fw, wob, fwb);
  wq_trans_kernel<<<dim3(12, 12 * NH), 256, 0, stream>>>(wq, wqTb);
  pe_add_kernel<<<NB / 256, 256, 0, stream>>>(tok, bufA, XbA);
  for (int it = 0; it < 13; ++it) {
    int l = (it == 0) ? 0 : it - 1;  // layer 0 applied twice (faithful)
    gemm_q_kernel<<<dim3(32, NH), 256, 0, stream>>>(
        XbA, wqTb + (size_t)l * (NH * HD * EMB), Qbf, Qtb);
    attn_mfma_kernel<<<dim3(64, NH), 256, 0, stream>>>(Qbf, Qtb, Zcb);
    gemm_out_kernel<<<dim3(32, 6, 2), 256, 0, stream>>>(
        wob + (size_t)l * (EMB * EMB), Zcb, bufB);
    ln_kernel<<<BS_TOK / 4, 256, 0, stream>>>(bufA, bufB, g1 + l * EMB, b1 + l * EMB,
                                              bufD, L1b);
    gemm_ffn_kernel<<<dim3(16, 12, 2), 256, 0, stream>>>(
        L1b, fwb + (size_t)l * (EMB * EMB), fb + l * EMB, bufB);
    float* ln2_dst = (it == 12) ? (float*)d_out : bufA;
    ln_kernel<<<BS_TOK / 4, 256, 0, stream>>>(bufD, bufB, g2 + l * EMB, b2 + l * EMB,
                                              ln2_dst, XbA);
  }
}